// Round 5
// baseline (7470.929 us; speedup 1.0000x reference)
//
#include <hip/hip_runtime.h>
#include <hip/hip_bf16.h>
#include <cstdint>
#include <cstddef>
#include <math.h>

using bf16 = __hip_bfloat16;
typedef __bf16 bf16x8 __attribute__((ext_vector_type(8)));
typedef float f32x4 __attribute__((ext_vector_type(4)));

// ---------------- constants ----------------
static constexpr int NHEAD = 12;
static constexpr int NTOK  = 211;   // 210 patches + cls
static constexpr int DEPTH = 11;

// ---------------- global->LDS direct load ----------------
static __device__ __forceinline__ void gload_lds16(const bf16* g, bf16* lds) {
  __builtin_amdgcn_global_load_lds(
      (const __attribute__((address_space(1))) uint32_t*)g,
      (__attribute__((address_space(3))) uint32_t*)lds,
      16, 0, 0);
}

#define SCHED_FENCE() __builtin_amdgcn_sched_barrier(0)
#define PHASE_BARRIER() do { SCHED_FENCE(); __builtin_amdgcn_s_barrier(); \
                             asm volatile("" ::: "memory"); SCHED_FENCE(); } while (0)

// ---------------- ring-3 multi-phase TN GEMM (T2+T3+T4+T5) ----------------
// C[M,N] = A[M,K] * Bt[N,K]^T (+bias,+gelu,+residual)
// BM=256, BN=128, BK=64; 512 threads = 8 waves (4M x 2N), wave owns 64x64.
// LDS: ring of 3 K-tile slots, slot = A[256][64] + B[128][64] = 48KB -> 144KB dynamic.
// 4 phases per K-tile, 8 MFMA per phase per wave.
// Stage K-tile T+2 during T's phases (2 gload_lds at p=0,1,2) -> stage slot is
// provably idle (its old occupant T-1 finished at T-1's last barrier).
// Certify T+1 at T's last phase with vmcnt(6) (= T+2's 6 in-flight loads): loads
// get a full K-tile (~4-8 phases) of latency slack; never drains until the tail.
// LDS chunk swizzle: phys_ch = ch ^ (row&7) within each 128B row (both-sides:
// inverse-permuted global source + swizzled read; read conflict <= 2-way = free).
template <bool GELU, bool RES, typename CT>
__global__ __launch_bounds__(512, 2) void gemm8p(
    const bf16* __restrict__ A, const bf16* __restrict__ Bt,
    const float* __restrict__ bias, const float* __restrict__ res,
    CT* __restrict__ C, int M, int N, int K, int gn)
{
  extern __shared__ bf16 lds[];     // 3 * 24576 elems

  const int tid = threadIdx.x;
  const int w = tid >> 6;
  const int l = tid & 63;
  const int lr = l & 15, lg = l >> 4;
  const int wr = w >> 1, wc = w & 1;      // wave tile: rows wr*64, cols wc*64

  // bijective XCD swizzle (m204), N-fastest tile order
  const int nwg = gridDim.x;
  const int lin = blockIdx.x;
  const int q = nwg >> 3, r = nwg & 7;
  const int xcd = lin & 7, pos = lin >> 3;
  const int wg = (xcd < r ? xcd * (q + 1) : r * (q + 1) + (xcd - r) * q) + pos;
  const int bm0 = (wg / gn) * 256;
  const int bn0 = (wg % gn) * 128;

  f32x4 acc[4][4];
#pragma unroll
  for (int i = 0; i < 4; ++i)
#pragma unroll
    for (int j = 0; j < 4; ++j) acc[i][j] = f32x4{0.f, 0.f, 0.f, 0.f};

  // ---- staging precompute: 6 chunks (16B) per thread per K-tile ----
  // chunk c = j*512 + tid; c<2048 -> A (row=c>>3), else B (row=(c-2048)>>3).
  // phys chunk pch=c&7 holds logical ch = pch ^ (row&7).
  const bf16* sbase[6];
  size_t goff[6];
  int loff[6];
#pragma unroll
  for (int j = 0; j < 6; ++j) {
    const int c = j * 512 + tid;
    const bool isa = c < 2048;
    const int cc = isa ? c : c - 2048;
    const int row = cc >> 3;
    const int ch = (cc & 7) ^ (row & 7);
    int grow = isa ? bm0 + row : bn0 + row;
    if (isa && grow >= M) grow = M - 1;
    sbase[j] = isa ? A : Bt;
    goff[j] = (size_t)grow * K + ch * 8;
    loff[j] = c * 8;
  }

  const int nt = K >> 6;   // K-tiles of 64

  // per-lane constant swizzled chunk offsets (row&7 == lr&7 for all frag rows)
  const int chsw0 = ((lg) ^ (lr & 7)) * 8;
  const int chsw1 = ((4 + lg) ^ (lr & 7)) * 8;

  // ---- prologue: stage K-tiles 0 and 1, certify tile 0 ----
#pragma unroll
  for (int j = 0; j < 6; ++j) gload_lds16(sbase[j] + goff[j], lds + loff[j]);
#pragma unroll
  for (int j = 0; j < 6; ++j) gload_lds16(sbase[j] + goff[j] + 64, lds + 24576 + loff[j]);
  asm volatile("s_waitcnt vmcnt(6)" ::: "memory");
  PHASE_BARRIER();

  int scur = 0;
  for (int T = 0; T < nt; ++T) {
    int sstage = scur + 2; if (sstage >= 3) sstage -= 3;
    const bool do_stage = (T + 2 < nt);
    const bf16* const Asl = lds + scur * 24576;
    const bf16* const Bsl = Asl + 16384;
    bf16* const Ssl = lds + sstage * 24576;
    const size_t kof = (size_t)(T + 2) * 64;

#pragma unroll
    for (int p = 0; p < 4; ++p) {
      const int qm = p >> 1, qn = p & 1;
      // ds-reads for this phase's 8 MFMA
      bf16x8 af[2][2], bv[2][2];
#pragma unroll
      for (int mi = 0; mi < 2; ++mi) {
        const int arow = wr * 64 + qm * 32 + mi * 16 + lr;
        af[mi][0] = *reinterpret_cast<const bf16x8*>(Asl + arow * 64 + chsw0);
        af[mi][1] = *reinterpret_cast<const bf16x8*>(Asl + arow * 64 + chsw1);
      }
#pragma unroll
      for (int ni = 0; ni < 2; ++ni) {
        const int brow = wc * 64 + qn * 32 + ni * 16 + lr;
        bv[ni][0] = *reinterpret_cast<const bf16x8*>(Bsl + brow * 64 + chsw0);
        bv[ni][1] = *reinterpret_cast<const bf16x8*>(Bsl + brow * 64 + chsw1);
      }
      // stage 2 chunks of K-tile T+2 (phases 0..2)
      if (do_stage && p < 3) {
        gload_lds16(sbase[2 * p] + goff[2 * p] + kof, Ssl + loff[2 * p]);
        gload_lds16(sbase[2 * p + 1] + goff[2 * p + 1] + kof, Ssl + loff[2 * p + 1]);
      }
      PHASE_BARRIER();
      __builtin_amdgcn_s_setprio(1);
#pragma unroll
      for (int mi = 0; mi < 2; ++mi)
#pragma unroll
        for (int ni = 0; ni < 2; ++ni) {
          acc[qm * 2 + mi][qn * 2 + ni] = __builtin_amdgcn_mfma_f32_16x16x32_bf16(
              af[mi][0], bv[ni][0], acc[qm * 2 + mi][qn * 2 + ni], 0, 0, 0);
          acc[qm * 2 + mi][qn * 2 + ni] = __builtin_amdgcn_mfma_f32_16x16x32_bf16(
              af[mi][1], bv[ni][1], acc[qm * 2 + mi][qn * 2 + ni], 0, 0, 0);
        }
      __builtin_amdgcn_s_setprio(0);
      if (p == 3) {
        if (T + 2 < nt)      { asm volatile("s_waitcnt vmcnt(6)" ::: "memory"); }
        else if (T + 1 < nt) { asm volatile("s_waitcnt vmcnt(0)" ::: "memory"); }
      }
      PHASE_BARRIER();
    }
    scur = (scur == 2) ? 0 : scur + 1;
  }

  // ---- epilogue ----
#pragma unroll
  for (int mi = 0; mi < 4; ++mi) {
#pragma unroll
    for (int ni = 0; ni < 4; ++ni) {
      const int col = bn0 + wc * 64 + ni * 16 + lr;
      const float bvl = bias[col];
#pragma unroll
      for (int r2 = 0; r2 < 4; ++r2) {
        const int row = bm0 + wr * 64 + mi * 16 + lg * 4 + r2;
        if (row < M) {
          float v = acc[mi][ni][r2] + bvl;
          if constexpr (GELU) v = 0.5f * v * (1.f + erff(v * 0.7071067811865475f));
          if constexpr (RES) v += res[(size_t)row * N + col];
          if constexpr (sizeof(CT) == 4) {
            C[(size_t)row * N + col] = v;
          } else {
            C[(size_t)row * N + col] = __float2bfloat16(v);
          }
        }
      }
    }
  }
}

// ---------------- fused attention: one block per (bb, head) ----------------
template <int NKF>  // NKF = padded token count / 16
__global__ __launch_bounds__(256) void attn_kernel(
    const bf16* __restrict__ qkv, bf16* __restrict__ ao, int ntok)
{
  constexpr int NPAD = NKF * 16;
  __shared__ bf16 Pl[4][16][NPAD];
  const int bb = blockIdx.x;
  const int h = blockIdx.y;
  const int tid = threadIdx.x;
  const int w = tid >> 6, l = tid & 63;
  const int lr = l & 15, lg = l >> 4;
  const __bf16* base = reinterpret_cast<const __bf16*>(qkv) + (size_t)bb * ntok * 2304 + h * 64;

  for (int qt = w; qt < NKF; qt += 4) {
    int qrow = qt * 16 + lr; if (qrow >= ntok) qrow = ntok - 1;
    const __bf16* qp = base + (size_t)qrow * 2304 + lg * 8;
    const bf16x8 qf0 = *reinterpret_cast<const bf16x8*>(qp);
    const bf16x8 qf1 = *reinterpret_cast<const bf16x8*>(qp + 32);

    f32x4 s[NKF];
#pragma unroll
    for (int kf = 0; kf < NKF; ++kf) {
      int krow = kf * 16 + lr; if (krow >= ntok) krow = ntok - 1;
      const __bf16* kp = base + (size_t)krow * 2304 + 768 + lg * 8;
      f32x4 a = f32x4{0.f, 0.f, 0.f, 0.f};
      a = __builtin_amdgcn_mfma_f32_16x16x32_bf16(qf0, *reinterpret_cast<const bf16x8*>(kp), a, 0, 0, 0);
      a = __builtin_amdgcn_mfma_f32_16x16x32_bf16(qf1, *reinterpret_cast<const bf16x8*>(kp + 32), a, 0, 0, 0);
      s[kf] = a;
    }

    float rs[4];
#pragma unroll
    for (int r = 0; r < 4; ++r) {
      float mx = -1e30f;
#pragma unroll
      for (int kf = 0; kf < NKF; ++kf)
        if (kf * 16 + lr < ntok) mx = fmaxf(mx, s[kf][r]);
#pragma unroll
      for (int d = 1; d < 16; d <<= 1) mx = fmaxf(mx, __shfl_xor(mx, d));
      float sum = 0.f;
#pragma unroll
      for (int kf = 0; kf < NKF; ++kf) {
        float p = 0.f;
        if (kf * 16 + lr < ntok) p = __expf((s[kf][r] - mx) * 0.125f);
        sum += p;
        Pl[w][lg * 4 + r][kf * 16 + lr] = __float2bfloat16(p);
      }
#pragma unroll
      for (int d = 1; d < 16; d <<= 1) sum += __shfl_xor(sum, d);
      rs[r] = sum;
    }

    f32x4 o[4];
#pragma unroll
    for (int ni = 0; ni < 4; ++ni) o[ni] = f32x4{0.f, 0.f, 0.f, 0.f};
    const __bf16* vbase = base + 1536;
#pragma unroll
    for (int ks = 0; ks < NPAD / 32; ++ks) {
      const bf16x8 pa = *reinterpret_cast<const bf16x8*>(&Pl[w][lr][ks * 32 + lg * 8]);
#pragma unroll
      for (int ni = 0; ni < 4; ++ni) {
        bf16x8 vb;
#pragma unroll
        for (int j = 0; j < 8; ++j) {
          int vk = ks * 32 + lg * 8 + j; if (vk >= ntok) vk = ntok - 1;
          vb[j] = vbase[(size_t)vk * 2304 + ni * 16 + lr];
        }
        o[ni] = __builtin_amdgcn_mfma_f32_16x16x32_bf16(pa, vb, o[ni], 0, 0, 0);
      }
    }
#pragma unroll
    for (int ni = 0; ni < 4; ++ni)
#pragma unroll
      for (int r = 0; r < 4; ++r) {
        int qq = qt * 16 + lg * 4 + r;
        if (qq < ntok) {
          float val = o[ni][r] / rs[r];
          ao[((size_t)bb * ntok + qq) * 768 + h * 64 + ni * 16 + lr] = __float2bfloat16(val);
        }
      }
  }
}

// ---------------- layernorm: f32 in -> bf16 out, one wave per row ----------------
__global__ __launch_bounds__(256) void ln_kernel(
    const float* __restrict__ x, const float* __restrict__ g, const float* __restrict__ b,
    bf16* __restrict__ out, int Mrows)
{
  int row = blockIdx.x * 4 + (threadIdx.x >> 6);
  if (row >= Mrows) return;
  int l = threadIdx.x & 63;
  const float* xr = x + (size_t)row * 768;
  float v[12]; float s = 0.f;
#pragma unroll
  for (int i = 0; i < 12; ++i) { v[i] = xr[l + i * 64]; s += v[i]; }
#pragma unroll
  for (int d = 1; d < 64; d <<= 1) s += __shfl_xor(s, d);
  float mean = s * (1.f / 768.f);
  float s2 = 0.f;
#pragma unroll
  for (int i = 0; i < 12; ++i) { float t = v[i] - mean; s2 += t * t; }
#pragma unroll
  for (int d = 1; d < 64; d <<= 1) s2 += __shfl_xor(s2, d);
  float rstd = rsqrtf(s2 * (1.f / 768.f) + 1e-6f);
  bf16* orow = out + (size_t)row * 768;
#pragma unroll
  for (int i = 0; i < 12; ++i) {
    orow[l + i * 64] = __float2bfloat16((v[i] - mean) * rstd * g[l + i * 64] + b[l + i * 64]);
  }
}

// ---------------- head layernorm (row 0 of each sequence) -> output (f32) ----------------
__global__ __launch_bounds__(256) void ln_head_kernel(
    const float* __restrict__ x, int tokstride, const float* __restrict__ g,
    const float* __restrict__ b, float* __restrict__ out, int nbb, int mode)
{
  int bb = blockIdx.x * 4 + (threadIdx.x >> 6);
  if (bb >= nbb) return;
  int l = threadIdx.x & 63;
  const float* xr = x + (size_t)bb * tokstride * 768;
  float v[12]; float s = 0.f;
#pragma unroll
  for (int i = 0; i < 12; ++i) { v[i] = xr[l + i * 64]; s += v[i]; }
#pragma unroll
  for (int d = 1; d < 64; d <<= 1) s += __shfl_xor(s, d);
  float mean = s * (1.f / 768.f);
  float s2 = 0.f;
#pragma unroll
  for (int i = 0; i < 12; ++i) { float t = v[i] - mean; s2 += t * t; }
#pragma unroll
  for (int d = 1; d < 64; d <<= 1) s2 += __shfl_xor(s2, d);
  float rstd = rsqrtf(s2 * (1.f / 768.f) + 1e-6f);
  float scale = mode ? 0.25f : 1.f;
  int b_ = mode ? (bb & 63) : bb;
  int off = mode ? (1 + (bb >> 6)) * 768 : 0;
  float* orow = out + (size_t)b_ * 3840 + off;
#pragma unroll
  for (int i = 0; i < 12; ++i) {
    orow[l + i * 64] = ((v[i] - mean) * rstd * g[l + i * 64] + b[l + i * 64]) * scale;
  }
}

// ---------------- weight transpose (R,C) f32 -> (C,R) bf16 ----------------
__global__ __launch_bounds__(256) void transpose_k(
    const float* __restrict__ in, bf16* __restrict__ out, int R, int C)
{
  __shared__ float tile[32][33];
  int c0 = blockIdx.x * 32, r0 = blockIdx.y * 32;
  int tx = threadIdx.x & 31, ty = threadIdx.x >> 5;  // ty 0..7
#pragma unroll
  for (int i = 0; i < 4; ++i) {
    int r = ty + i * 8;
    tile[r][tx] = in[(size_t)(r0 + r) * C + c0 + tx];
  }
  __syncthreads();
#pragma unroll
  for (int i = 0; i < 4; ++i) {
    int c = ty + i * 8;
    out[(size_t)(c0 + c) * R + r0 + tx] = __float2bfloat16(tile[tx][c]);
  }
}

// ---------------- f32 -> bf16 cast ----------------
__global__ void cast_kernel(const float* __restrict__ in, bf16* __restrict__ out, int n)
{
  int idx = blockIdx.x * 256 + threadIdx.x;
  if (idx < n) out[idx] = __float2bfloat16(in[idx]);
}

// ---------------- patch im2col (f32 -> bf16) ----------------
__global__ void im2col_kernel(const float* __restrict__ x, bf16* __restrict__ pm)
{
  int idx = blockIdx.x * 256 + threadIdx.x;
  if (idx >= 13440 * 768) return;
  int k = idx % 768;
  int m = idx / 768;
  int b = m / 210, p = m % 210;
  int py = p / 10, px = p % 10;
  int c = k >> 8, ij = k & 255, i = ij >> 4, j = ij & 15;
  pm[idx] = __float2bfloat16(x[(((size_t)b * 3 + c) * 256 + py * 12 + i) * 128 + px * 12 + j]);
}

// ---------------- assemble t = [cls | patches] + pos + SIE*sie[cid] (f32) ----------------
__global__ void assemble_kernel(
    const bf16* __restrict__ y, const float* __restrict__ cls, const float* __restrict__ pos,
    const float* __restrict__ sie, const int* __restrict__ cids, float* __restrict__ tA)
{
  int idx = blockIdx.x * 256 + threadIdx.x;
  if (idx >= 13504 * 768) return;
  int d = idx % 768;
  int t = (idx / 768) % 211;
  int b = idx / (768 * 211);
  float v = pos[t * 768 + d] + 3.0f * sie[cids[b] * 768 + d];
  if (t == 0) v += cls[d];
  else v += __bfloat162float(y[((size_t)b * 210 + (t - 1)) * 768 + d]);
  tA[idx] = v;
}

// ---------------- gather the 4 shuffled segments into a 256-batch of 53 tokens ----------------
__global__ void gather_kernel(const float* __restrict__ tA, float* __restrict__ tB)
{
  int idx = blockIdx.x * 256 + threadIdx.x;
  if (idx >= 256 * 53 * 768) return;
  int d = idx % 768;
  int jj = (idx / 768) % 53;
  int bb = idx / (768 * 53);
  int i = bb >> 6, b = bb & 63;
  int src;
  if (jj == 0) src = 0;
  else {
    int jx = i * 52 + (jj - 1);
    int mm = (jx & 1) * 105 + (jx >> 1);
    src = (mm < 206) ? (5 + mm) : (1 + (mm - 206));
  }
  tB[idx] = tA[((size_t)b * 211 + src) * 768 + d];
}

// ---------------- host orchestration ----------------
struct BlkP {
  const float *ln1_g, *ln1_b, *qkv_w, *qkv_b, *proj_w, *proj_b;
  const float *ln2_g, *ln2_b, *fc1_w, *fc1_b, *fc2_w, *fc2_b;
};

extern "C" void kernel_launch(void* const* d_in, const int* in_sizes, int n_in,
                              void* d_out, int out_size, void* d_ws, size_t ws_size,
                              hipStream_t stream)
{
  (void)in_sizes; (void)n_in; (void)out_size; (void)ws_size;
  const float* xin   = (const float*)d_in[0];
  const int*   cids  = (const int*)  d_in[1];
  const float* convw = (const float*)d_in[2];
  const float* convb = (const float*)d_in[3];
  const float* cls   = (const float*)d_in[4];
  const float* pos   = (const float*)d_in[5];
  const float* sie   = (const float*)d_in[6];
  float* out = (float*)d_out;

  // allow 144KB dynamic LDS on the GEMM instantiations (idempotent)
  constexpr int SMEM = 3 * 24576 * 2;   // 147456 bytes
  static bool attr_done = [] {
    hipFuncSetAttribute(reinterpret_cast<const void*>(&gemm8p<false, false, bf16>),
                        hipFuncAttributeMaxDynamicSharedMemorySize, SMEM);
    hipFuncSetAttribute(reinterpret_cast<const void*>(&gemm8p<false, true, float>),
                        hipFuncAttributeMaxDynamicSharedMemorySize, SMEM);
    hipFuncSetAttribute(reinterpret_cast<const void*>(&gemm8p<true, false, bf16>),
                        hipFuncAttributeMaxDynamicSharedMemorySize, SMEM);
    return true;
  }();
  (void)attr_done;

  // workspace layout (bytes)
  char* ws = (char*)d_ws;
  bf16*  qkvT = (bf16*)(ws + 0);            // 2304x768 bf16 (also convw_bf slot)
  bf16*  projT = (bf16*)(ws + 3538944);     // 768x768
  bf16*  fc1T = (bf16*)(ws + 4718592);      // 3072x768
  bf16*  fc2T = (bf16*)(ws + 9437184);      // 768x3072
  float* tA   = (float*)(ws + 14155776);    // 13504x768 f32
  float* tB   = (float*)(ws + 55640064);    // 13568x768 f32
  bf16*  hb   = (bf16*)(ws + 97320960);     // 13568x768 bf16
  bf16*  big  = (bf16*)(ws + 118161408);    // qkv / mlp-mid / im2col (79.5MB)
  bf16*  ao   = (bf16*)(ws + 201523200);    // 13568x768 bf16

  dim3 blk(256);

  auto apply_block = [&](float* xbuf, const BlkP& p, int nb, int ntok_) {
    const int M = nb * ntok_;
    const int gm = (M + 255) / 256;
    transpose_k<<<dim3(2304 / 32, 768 / 32), blk, 0, stream>>>(p.qkv_w, qkvT, 768, 2304);
    transpose_k<<<dim3(768 / 32, 768 / 32), blk, 0, stream>>>(p.proj_w, projT, 768, 768);
    transpose_k<<<dim3(3072 / 32, 768 / 32), blk, 0, stream>>>(p.fc1_w, fc1T, 768, 3072);
    transpose_k<<<dim3(768 / 32, 3072 / 32), blk, 0, stream>>>(p.fc2_w, fc2T, 3072, 768);
    ln_kernel<<<dim3((M + 3) / 4), blk, 0, stream>>>(xbuf, p.ln1_g, p.ln1_b, hb, M);
    gemm8p<false, false, bf16><<<dim3(gm * 18), dim3(512), SMEM, stream>>>(
        hb, qkvT, p.qkv_b, nullptr, big, M, 2304, 768, 18);
    if (ntok_ == NTOK)
      attn_kernel<14><<<dim3(nb, NHEAD), blk, 0, stream>>>(big, ao, ntok_);
    else
      attn_kernel<4><<<dim3(nb, NHEAD), blk, 0, stream>>>(big, ao, ntok_);
    gemm8p<false, true, float><<<dim3(gm * 6), dim3(512), SMEM, stream>>>(
        ao, projT, p.proj_b, xbuf, xbuf, M, 768, 768, 6);
    ln_kernel<<<dim3((M + 3) / 4), blk, 0, stream>>>(xbuf, p.ln2_g, p.ln2_b, hb, M);
    gemm8p<true, false, bf16><<<dim3(gm * 24), dim3(512), SMEM, stream>>>(
        hb, fc1T, p.fc1_b, nullptr, big, M, 3072, 768, 24);
    gemm8p<false, true, float><<<dim3(gm * 6), dim3(512), SMEM, stream>>>(
        big, fc2T, p.fc2_b, xbuf, xbuf, M, 768, 3072, 6);
  };

  // 1) patch embed: im2col -> GEMM(conv) -> assemble
  {
    int total = 13440 * 768;
    im2col_kernel<<<dim3((total + 255) / 256), blk, 0, stream>>>(xin, big);
    int nw = 768 * 768;
    cast_kernel<<<dim3((nw + 255) / 256), blk, 0, stream>>>(convw, qkvT, nw);
    gemm8p<false, false, bf16><<<dim3(53 * 6), dim3(512), SMEM, stream>>>(
        big, qkvT, convb, nullptr, ao, 13440, 768, 768, 6);
    total = 13504 * 768;
    assemble_kernel<<<dim3((total + 255) / 256), blk, 0, stream>>>(ao, cls, pos, sie, cids, tA);
  }

  // 2) 11 stacked blocks (lead-dim DEPTH params)
  const float* bp[12];
  for (int i = 0; i < 12; ++i) bp[i] = (const float*)d_in[7 + i];
  for (int dd = 0; dd < DEPTH; ++dd) {
    BlkP p;
    p.ln1_g = bp[0] + dd * 768;                p.ln1_b = bp[1] + dd * 768;
    p.qkv_w = bp[2] + (size_t)dd * 768 * 2304; p.qkv_b = bp[3] + dd * 2304;
    p.proj_w = bp[4] + (size_t)dd * 768 * 768; p.proj_b = bp[5] + dd * 768;
    p.ln2_g = bp[6] + dd * 768;                p.ln2_b = bp[7] + dd * 768;
    p.fc1_w = bp[8] + (size_t)dd * 768 * 3072; p.fc1_b = bp[9] + dd * 3072;
    p.fc2_w = bp[10] + (size_t)dd * 3072 * 768; p.fc2_b = bp[11] + dd * 768;
    apply_block(tA, p, 64, NTOK);
  }

  // 3) b1 branch: f0 = LN(block(t))[:,0]
  hipMemcpyAsync(tB, tA, (size_t)13504 * 768 * 4, hipMemcpyDeviceToDevice, stream);
  {
    BlkP p;
    p.ln1_g = (const float*)d_in[19]; p.ln1_b = (const float*)d_in[20];
    p.qkv_w = (const float*)d_in[21]; p.qkv_b = (const float*)d_in[22];
    p.proj_w = (const float*)d_in[23]; p.proj_b = (const float*)d_in[24];
    p.ln2_g = (const float*)d_in[25]; p.ln2_b = (const float*)d_in[26];
    p.fc1_w = (const float*)d_in[27]; p.fc1_b = (const float*)d_in[28];
    p.fc2_w = (const float*)d_in[29]; p.fc2_b = (const float*)d_in[30];
    apply_block(tB, p, 64, NTOK);
    ln_head_kernel<<<dim3(16), blk, 0, stream>>>(
        tB, NTOK, (const float*)d_in[31], (const float*)d_in[32], out, 64, 0);
  }

  // 4) b2 branch: 4 shuffled segments batched as 256 sequences of 53 tokens
  {
    int total = 256 * 53 * 768;
    gather_kernel<<<dim3((total + 255) / 256), blk, 0, stream>>>(tA, tB);
    BlkP p;
    p.ln1_g = (const float*)d_in[33]; p.ln1_b = (const float*)d_in[34];
    p.qkv_w = (const float*)d_in[35]; p.qkv_b = (const float*)d_in[36];
    p.proj_w = (const float*)d_in[37]; p.proj_b = (const float*)d_in[38];
    p.ln2_g = (const float*)d_in[39]; p.ln2_b = (const float*)d_in[40];
    p.fc1_w = (const float*)d_in[41]; p.fc1_b = (const float*)d_in[42];
    p.fc2_w = (const float*)d_in[43]; p.fc2_b = (const float*)d_in[44];
    apply_block(tB, p, 256, 53);
    ln_head_kernel<<<dim3(64), blk, 0, stream>>>(
        tB, 53, (const float*)d_in[45], (const float*)d_in[46], out, 256, 1);
  }
}

// Round 7
// 6592.654 us; speedup vs baseline: 1.1332x; 1.1332x over previous
//
#include <hip/hip_runtime.h>
#include <hip/hip_bf16.h>
#include <cstdint>
#include <cstddef>
#include <math.h>

using bf16 = __hip_bfloat16;
typedef __bf16 bf16x8 __attribute__((ext_vector_type(8)));
typedef float f32x4 __attribute__((ext_vector_type(4)));

// ---------------- constants ----------------
static constexpr int NHEAD = 12;
static constexpr int NTOK  = 211;   // 210 patches + cls
static constexpr int DEPTH = 11;

// ---------------- global->LDS direct load ----------------
static __device__ __forceinline__ void gload_lds16(const bf16* g, bf16* lds) {
  __builtin_amdgcn_global_load_lds(
      (const __attribute__((address_space(1))) uint32_t*)g,
      (__attribute__((address_space(3))) uint32_t*)lds,
      16, 0, 0);
}

#define SCHED_FENCE() __builtin_amdgcn_sched_barrier(0)
#define PHASE_BARRIER() do { SCHED_FENCE(); __builtin_amdgcn_s_barrier(); \
                             asm volatile("" ::: "memory"); SCHED_FENCE(); } while (0)

__device__ __forceinline__ float gelu_f(float x) {
  // tanh-form GELU; |err| vs erf-form < 3e-3 absolute (amortized by fc2)
  float u = x * (0.7978845608f + 0.0356774081f * x * x);
  float t = 1.f - 2.f / (__expf(2.f * u) + 1.f);
  return 0.5f * x * (1.f + t);
}

static __device__ __forceinline__ unsigned short bf16_bits(float x) {
  return __builtin_bit_cast(unsigned short, __float2bfloat16(x));
}

// ---------------- 256x256 K-half-pipelined TN GEMM (T2+T3+T4+T5) ----------------
// C[M,N] = A[M,K] * Bt[N,K]^T (+bias,+gelu,+residual)
// BM=BN=256, BK=64; 512 thr = 8 waves (2M x 4N), wave owns 128x64 -> per K-tile:
// 64 MFMA : 24 ds_read_b128 per wave (2.67:1, MFMA-dominant vs LDS pipe).
// LDS: 4 half-slots (slot h&3), half h = A[256][32] + B[256][32] (32KB), k-range
// [h*32, h*32+32). Tile T consumes halves 2T (p0,p1) and 2T+1 (p2,p3).
// Prefetch depth 3 halves: tile T issues A/B of half 2T+3 at p0/p1 and of half
// 2T+4 at p2/p3; certify 2T+1 at end-p1 and 2T+2 at end-p3, both vmcnt(8)
// (= 2 newer halves x 4 loads in flight) -- never drains until the last tile.
// Swizzle: phys_ch = ch ^ ((row>>1)&3) within each 64B row (2-way conflict =
// free); staging pre-permutes the GLOBAL source, reads apply the same XOR.
template <bool GELU, bool RES, typename CT>
__global__ __launch_bounds__(512, 2) void gemm4p(
    const bf16* __restrict__ A, const bf16* __restrict__ Bt,
    const float* __restrict__ bias, const float* __restrict__ res,
    CT* __restrict__ C, int M, int N, int K, int gn)
{
  extern __shared__ bf16 lds[];     // 4 * 16384 elems = 128 KB

  const int tid = threadIdx.x;
  const int w = tid >> 6;
  const int l = tid & 63;
  const int lr = l & 15, lg = l >> 4;
  const int wm = w >> 2, wn = w & 3;       // wave: rows wm*128, cols wn*64

  // bijective XCD swizzle (m204), N-fastest tile order
  const int nwg = gridDim.x;
  const int lin = blockIdx.x;
  const int q = nwg >> 3, r = nwg & 7;
  const int xcd = lin & 7, pos = lin >> 3;
  const int wg = (xcd < r ? xcd * (q + 1) : r * (q + 1) + (xcd - r) * q) + pos;
  const int bm0 = (wg / gn) * 256;
  const int bn0 = (wg % gn) * 256;

  f32x4 acc[8][4];
#pragma unroll
  for (int i = 0; i < 8; ++i)
#pragma unroll
    for (int j = 0; j < 4; ++j) acc[i][j] = f32x4{0.f, 0.f, 0.f, 0.f};

  // staging precompute: per half, thread stages 2 A-chunks + 2 B-chunks (16B).
  // phys chunk c = j*512+tid: row = c>>2, pch = c&3 holds logical
  // ch = pch ^ ((row>>1)&3); global elem = row*K + ch*8 (+ h*32 per half).
  size_t aof[2], bof[2]; int adst[2], bdst[2];
#pragma unroll
  for (int j = 0; j < 2; ++j) {
    const int c = j * 512 + tid;
    const int row = c >> 2;
    const int ch = (c & 3) ^ ((row >> 1) & 3);
    int ar = bm0 + row; if (ar >= M) ar = M - 1;
    aof[j] = (size_t)ar * K + ch * 8;
    bof[j] = (size_t)(bn0 + row) * K + ch * 8;
    adst[j] = c * 8;
    bdst[j] = 8192 + c * 8;
  }

  const int nt = K >> 6;
  const int nh = nt * 2;

  auto stA = [&](int h) {
    bf16* s = lds + (h & 3) * 16384; const size_t ko = (size_t)h * 32;
    gload_lds16(A + aof[0] + ko, s + adst[0]);
    gload_lds16(A + aof[1] + ko, s + adst[1]);
  };
  auto stB = [&](int h) {
    bf16* s = lds + (h & 3) * 16384; const size_t ko = (size_t)h * 32;
    gload_lds16(Bt + bof[0] + ko, s + bdst[0]);
    gload_lds16(Bt + bof[1] + ko, s + bdst[1]);
  };

  // ---- prologue: halves 0,1,2 in flight; certify half 0 ----
  stA(0); stB(0); stA(1); stB(1); stA(2); stB(2);
  asm volatile("s_waitcnt vmcnt(8)" ::: "memory");
  PHASE_BARRIER();

  const int swz = (lg ^ ((lr >> 1) & 3)) * 8;    // per-lane swizzled k-chunk
  const int arow = wm * 128 + lr;                 // + mi*16
  const int brow = wn * 64 + lr;                  // + ni*16

  for (int T = 0; T < nt; ++T) {
    const bf16* s0 = lds + ((2 * T) & 3) * 16384;
    const bf16* s1 = lds + ((2 * T + 1) & 3) * 16384;
    const bool pf0 = (2 * T + 3 < nh);
    const bool pf1 = (2 * T + 4 < nh);
    bf16x8 bv[4], af[4];

    // ---- p0: half 2T, mi 0-3 ----
#pragma unroll
    for (int ni = 0; ni < 4; ++ni)
      bv[ni] = *(const bf16x8*)(s0 + 8192 + (brow + ni * 16) * 32 + swz);
#pragma unroll
    for (int mi = 0; mi < 4; ++mi)
      af[mi] = *(const bf16x8*)(s0 + (arow + mi * 16) * 32 + swz);
    if (pf0) stA(2 * T + 3);
    PHASE_BARRIER();
    __builtin_amdgcn_s_setprio(1);
#pragma unroll
    for (int mi = 0; mi < 4; ++mi)
#pragma unroll
      for (int ni = 0; ni < 4; ++ni)
        acc[mi][ni] = __builtin_amdgcn_mfma_f32_16x16x32_bf16(af[mi], bv[ni], acc[mi][ni], 0, 0, 0);
    __builtin_amdgcn_s_setprio(0);
    PHASE_BARRIER();

    // ---- p1: half 2T, mi 4-7 (bv reused) ----
#pragma unroll
    for (int mi = 0; mi < 4; ++mi)
      af[mi] = *(const bf16x8*)(s0 + (arow + 64 + mi * 16) * 32 + swz);
    if (pf0) stB(2 * T + 3);
    PHASE_BARRIER();
    __builtin_amdgcn_s_setprio(1);
#pragma unroll
    for (int mi = 0; mi < 4; ++mi)
#pragma unroll
      for (int ni = 0; ni < 4; ++ni)
        acc[4 + mi][ni] = __builtin_amdgcn_mfma_f32_16x16x32_bf16(af[mi], bv[ni], acc[4 + mi][ni], 0, 0, 0);
    __builtin_amdgcn_s_setprio(0);
    if (pf0) { asm volatile("s_waitcnt vmcnt(8)" ::: "memory"); }
    else     { asm volatile("s_waitcnt vmcnt(0)" ::: "memory"); }
    PHASE_BARRIER();

    // ---- p2: half 2T+1, mi 0-3 ----
#pragma unroll
    for (int ni = 0; ni < 4; ++ni)
      bv[ni] = *(const bf16x8*)(s1 + 8192 + (brow + ni * 16) * 32 + swz);
#pragma unroll
    for (int mi = 0; mi < 4; ++mi)
      af[mi] = *(const bf16x8*)(s1 + (arow + mi * 16) * 32 + swz);
    if (pf1) stA(2 * T + 4);
    PHASE_BARRIER();
    __builtin_amdgcn_s_setprio(1);
#pragma unroll
    for (int mi = 0; mi < 4; ++mi)
#pragma unroll
      for (int ni = 0; ni < 4; ++ni)
        acc[mi][ni] = __builtin_amdgcn_mfma_f32_16x16x32_bf16(af[mi], bv[ni], acc[mi][ni], 0, 0, 0);
    __builtin_amdgcn_s_setprio(0);
    PHASE_BARRIER();

    // ---- p3: half 2T+1, mi 4-7 ----
#pragma unroll
    for (int mi = 0; mi < 4; ++mi)
      af[mi] = *(const bf16x8*)(s1 + (arow + 64 + mi * 16) * 32 + swz);
    if (pf1) stB(2 * T + 4);
    PHASE_BARRIER();
    __builtin_amdgcn_s_setprio(1);
#pragma unroll
    for (int mi = 0; mi < 4; ++mi)
#pragma unroll
      for (int ni = 0; ni < 4; ++ni)
        acc[4 + mi][ni] = __builtin_amdgcn_mfma_f32_16x16x32_bf16(af[mi], bv[ni], acc[4 + mi][ni], 0, 0, 0);
    __builtin_amdgcn_s_setprio(0);
    if (T + 1 < nt) {
      if (pf1) { asm volatile("s_waitcnt vmcnt(8)" ::: "memory"); }
      else     { asm volatile("s_waitcnt vmcnt(4)" ::: "memory"); }
    }
    PHASE_BARRIER();
  }

  // ---- epilogue ----
#pragma unroll
  for (int mi = 0; mi < 8; ++mi) {
#pragma unroll
    for (int ni = 0; ni < 4; ++ni) {
      const int col = bn0 + wn * 64 + ni * 16 + lr;
      const float bvl = bias[col];
#pragma unroll
      for (int r2 = 0; r2 < 4; ++r2) {
        const int row = bm0 + wm * 128 + mi * 16 + lg * 4 + r2;
        if (row < M) {
          float v = acc[mi][ni][r2] + bvl;
          if constexpr (GELU) v = gelu_f(v);
          if constexpr (RES) v += res[(size_t)row * N + col];
          if constexpr (sizeof(CT) == 4) {
            C[(size_t)row * N + col] = v;
          } else {
            C[(size_t)row * N + col] = __float2bfloat16(v);
          }
        }
      }
    }
  }
}

// ---------------- fused attention: one block per (bb, head) ----------------
template <int NKF>  // NKF = padded token count / 16
__global__ __launch_bounds__(256) void attn_kernel(
    const bf16* __restrict__ qkv, bf16* __restrict__ ao, int ntok)
{
  constexpr int NPAD = NKF * 16;
  __shared__ bf16 Pl[4][16][NPAD];
  const int bb = blockIdx.x;
  const int h = blockIdx.y;
  const int tid = threadIdx.x;
  const int w = tid >> 6, l = tid & 63;
  const int lr = l & 15, lg = l >> 4;
  const __bf16* base = reinterpret_cast<const __bf16*>(qkv) + (size_t)bb * ntok * 2304 + h * 64;

  for (int qt = w; qt < NKF; qt += 4) {
    int qrow = qt * 16 + lr; if (qrow >= ntok) qrow = ntok - 1;
    const __bf16* qp = base + (size_t)qrow * 2304 + lg * 8;
    const bf16x8 qf0 = *reinterpret_cast<const bf16x8*>(qp);
    const bf16x8 qf1 = *reinterpret_cast<const bf16x8*>(qp + 32);

    f32x4 s[NKF];
#pragma unroll
    for (int kf = 0; kf < NKF; ++kf) {
      int krow = kf * 16 + lr; if (krow >= ntok) krow = ntok - 1;
      const __bf16* kp = base + (size_t)krow * 2304 + 768 + lg * 8;
      f32x4 a = f32x4{0.f, 0.f, 0.f, 0.f};
      a = __builtin_amdgcn_mfma_f32_16x16x32_bf16(qf0, *reinterpret_cast<const bf16x8*>(kp), a, 0, 0, 0);
      a = __builtin_amdgcn_mfma_f32_16x16x32_bf16(qf1, *reinterpret_cast<const bf16x8*>(kp + 32), a, 0, 0, 0);
      s[kf] = a;
    }

    float rs[4];
#pragma unroll
    for (int r = 0; r < 4; ++r) {
      float mx = -1e30f;
#pragma unroll
      for (int kf = 0; kf < NKF; ++kf)
        if (kf * 16 + lr < ntok) mx = fmaxf(mx, s[kf][r]);
#pragma unroll
      for (int d = 1; d < 16; d <<= 1) mx = fmaxf(mx, __shfl_xor(mx, d));
      float sum = 0.f;
#pragma unroll
      for (int kf = 0; kf < NKF; ++kf) {
        float p = 0.f;
        if (kf * 16 + lr < ntok) p = __expf((s[kf][r] - mx) * 0.125f);
        sum += p;
        Pl[w][lg * 4 + r][kf * 16 + lr] = __float2bfloat16(p);
      }
#pragma unroll
      for (int d = 1; d < 16; d <<= 1) sum += __shfl_xor(sum, d);
      rs[r] = sum;
    }

    f32x4 o[4];
#pragma unroll
    for (int ni = 0; ni < 4; ++ni) o[ni] = f32x4{0.f, 0.f, 0.f, 0.f};
    const __bf16* vbase = base + 1536;
#pragma unroll
    for (int ks = 0; ks < NPAD / 32; ++ks) {
      const bf16x8 pa = *reinterpret_cast<const bf16x8*>(&Pl[w][lr][ks * 32 + lg * 8]);
#pragma unroll
      for (int ni = 0; ni < 4; ++ni) {
        bf16x8 vb;
#pragma unroll
        for (int j = 0; j < 8; ++j) {
          int vk = ks * 32 + lg * 8 + j; if (vk >= ntok) vk = ntok - 1;
          vb[j] = vbase[(size_t)vk * 2304 + ni * 16 + lr];
        }
        o[ni] = __builtin_amdgcn_mfma_f32_16x16x32_bf16(pa, vb, o[ni], 0, 0, 0);
      }
    }
#pragma unroll
    for (int ni = 0; ni < 4; ++ni)
#pragma unroll
      for (int r = 0; r < 4; ++r) {
        int qq = qt * 16 + lg * 4 + r;
        if (qq < ntok) {
          float val = o[ni][r] / rs[r];
          ao[((size_t)bb * ntok + qq) * 768 + h * 64 + ni * 16 + lr] = __float2bfloat16(val);
        }
      }
  }
}

// ---------------- layernorm: f32 in -> bf16 out, one wave per row, float4 loads ----------------
__global__ __launch_bounds__(256) void ln_kernel(
    const float* __restrict__ x, const float* __restrict__ g, const float* __restrict__ b,
    bf16* __restrict__ out, int Mrows)
{
  int row = blockIdx.x * 4 + (threadIdx.x >> 6);
  if (row >= Mrows) return;
  int l = threadIdx.x & 63;
  const float4* xr = reinterpret_cast<const float4*>(x + (size_t)row * 768);
  float4 v[3]; float s = 0.f;
#pragma unroll
  for (int i = 0; i < 3; ++i) {
    v[i] = xr[l + i * 64];
    s += v[i].x + v[i].y + v[i].z + v[i].w;
  }
#pragma unroll
  for (int d = 1; d < 64; d <<= 1) s += __shfl_xor(s, d);
  float mean = s * (1.f / 768.f);
  float s2 = 0.f;
#pragma unroll
  for (int i = 0; i < 3; ++i) {
    float a0 = v[i].x - mean, a1 = v[i].y - mean, a2 = v[i].z - mean, a3 = v[i].w - mean;
    s2 += a0 * a0 + a1 * a1 + a2 * a2 + a3 * a3;
  }
#pragma unroll
  for (int d = 1; d < 64; d <<= 1) s2 += __shfl_xor(s2, d);
  float rstd = rsqrtf(s2 * (1.f / 768.f) + 1e-6f);
  const float4* g4 = reinterpret_cast<const float4*>(g);
  const float4* b4 = reinterpret_cast<const float4*>(b);
  unsigned short* orow = reinterpret_cast<unsigned short*>(out + (size_t)row * 768);
#pragma unroll
  for (int i = 0; i < 3; ++i) {
    float4 gg = g4[l + i * 64], bb = b4[l + i * 64];
    ushort4 pk;
    pk.x = bf16_bits((v[i].x - mean) * rstd * gg.x + bb.x);
    pk.y = bf16_bits((v[i].y - mean) * rstd * gg.y + bb.y);
    pk.z = bf16_bits((v[i].z - mean) * rstd * gg.z + bb.z);
    pk.w = bf16_bits((v[i].w - mean) * rstd * gg.w + bb.w);
    *reinterpret_cast<ushort4*>(orow + (l + i * 64) * 4) = pk;
  }
}

// ---------------- head layernorm (row 0 of each sequence) -> output (f32) ----------------
__global__ __launch_bounds__(256) void ln_head_kernel(
    const float* __restrict__ x, int tokstride, const float* __restrict__ g,
    const float* __restrict__ b, float* __restrict__ out, int nbb, int mode)
{
  int bb = blockIdx.x * 4 + (threadIdx.x >> 6);
  if (bb >= nbb) return;
  int l = threadIdx.x & 63;
  const float* xr = x + (size_t)bb * tokstride * 768;
  float v[12]; float s = 0.f;
#pragma unroll
  for (int i = 0; i < 12; ++i) { v[i] = xr[l + i * 64]; s += v[i]; }
#pragma unroll
  for (int d = 1; d < 64; d <<= 1) s += __shfl_xor(s, d);
  float mean = s * (1.f / 768.f);
  float s2 = 0.f;
#pragma unroll
  for (int i = 0; i < 12; ++i) { float t = v[i] - mean; s2 += t * t; }
#pragma unroll
  for (int d = 1; d < 64; d <<= 1) s2 += __shfl_xor(s2, d);
  float rstd = rsqrtf(s2 * (1.f / 768.f) + 1e-6f);
  float scale = mode ? 0.25f : 1.f;
  int b_ = mode ? (bb & 63) : bb;
  int off = mode ? (1 + (bb >> 6)) * 768 : 0;
  float* orow = out + (size_t)b_ * 3840 + off;
#pragma unroll
  for (int i = 0; i < 12; ++i) {
    orow[l + i * 64] = ((v[i] - mean) * rstd * g[l + i * 64] + b[l + i * 64]) * scale;
  }
}

// ---------------- fused 4-matrix weight transpose (R,C) f32 -> (C,R) bf16 ----------------
// m0: 768x2304 (qkv)  m1: 768x768 (proj)  m2: 768x3072 (fc1)  m3: 3072x768 (fc2)
__global__ __launch_bounds__(256) void transpose4_k(
    const float* __restrict__ w0, const float* __restrict__ w1,
    const float* __restrict__ w2, const float* __restrict__ w3,
    bf16* __restrict__ d0, bf16* __restrict__ d1,
    bf16* __restrict__ d2, bf16* __restrict__ d3)
{
  __shared__ float tile[32][33];
  int id = blockIdx.x;
  const float* in; bf16* out; int R, C, tt;
  if (id < 1728)      { in = w0; out = d0; R = 768;  C = 2304; tt = id; }
  else if (id < 2304) { in = w1; out = d1; R = 768;  C = 768;  tt = id - 1728; }
  else if (id < 4608) { in = w2; out = d2; R = 768;  C = 3072; tt = id - 2304; }
  else                { in = w3; out = d3; R = 3072; C = 768;  tt = id - 4608; }
  const int tc = C >> 5;
  int c0 = (tt % tc) * 32, r0 = (tt / tc) * 32;
  int tx = threadIdx.x & 31, ty = threadIdx.x >> 5;
#pragma unroll
  for (int i = 0; i < 4; ++i) {
    int rr = ty + i * 8;
    tile[rr][tx] = in[(size_t)(r0 + rr) * C + c0 + tx];
  }
  __syncthreads();
#pragma unroll
  for (int i = 0; i < 4; ++i) {
    int c = ty + i * 8;
    out[(size_t)(c0 + c) * R + r0 + tx] = __float2bfloat16(tile[tx][c]);
  }
}

// ---------------- f32 -> bf16 cast ----------------
__global__ void cast_kernel(const float* __restrict__ in, bf16* __restrict__ out, int n)
{
  int idx = blockIdx.x * 256 + threadIdx.x;
  if (idx < n) out[idx] = __float2bfloat16(in[idx]);
}

// ---------------- patch im2col (f32 -> bf16) ----------------
__global__ void im2col_kernel(const float* __restrict__ x, bf16* __restrict__ pm)
{
  int idx = blockIdx.x * 256 + threadIdx.x;
  if (idx >= 13440 * 768) return;
  int k = idx % 768;
  int m = idx / 768;
  int b = m / 210, p = m % 210;
  int py = p / 10, px = p % 10;
  int c = k >> 8, ij = k & 255, i = ij >> 4, j = ij & 15;
  pm[idx] = __float2bfloat16(x[(((size_t)b * 3 + c) * 256 + py * 12 + i) * 128 + px * 12 + j]);
}

// ---------------- assemble t = [cls | patches] + pos + SIE*sie[cid] (f32) ----------------
__global__ void assemble_kernel(
    const bf16* __restrict__ y, const float* __restrict__ cls, const float* __restrict__ pos,
    const float* __restrict__ sie, const int* __restrict__ cids, float* __restrict__ tA)
{
  int idx = blockIdx.x * 256 + threadIdx.x;
  if (idx >= 13504 * 768) return;
  int d = idx % 768;
  int t = (idx / 768) % 211;
  int b = idx / (768 * 211);
  float v = pos[t * 768 + d] + 3.0f * sie[cids[b] * 768 + d];
  if (t == 0) v += cls[d];
  else v += __bfloat162float(y[((size_t)b * 210 + (t - 1)) * 768 + d]);
  tA[idx] = v;
}

// ---------------- gather the 4 shuffled segments into a 256-batch of 53 tokens ----------------
__global__ void gather_kernel(const float* __restrict__ tA, float* __restrict__ tB)
{
  int idx = blockIdx.x * 256 + threadIdx.x;
  if (idx >= 256 * 53 * 768) return;
  int d = idx % 768;
  int jj = (idx / 768) % 53;
  int bb = idx / (768 * 53);
  int i = bb >> 6, b = bb & 63;
  int src;
  if (jj == 0) src = 0;
  else {
    int jx = i * 52 + (jj - 1);
    int mm = (jx & 1) * 105 + (jx >> 1);
    src = (mm < 206) ? (5 + mm) : (1 + (mm - 206));
  }
  tB[idx] = tA[((size_t)b * 211 + src) * 768 + d];
}

// ---------------- host orchestration ----------------
struct BlkP {
  const float *ln1_g, *ln1_b, *qkv_w, *qkv_b, *proj_w, *proj_b;
  const float *ln2_g, *ln2_b, *fc1_w, *fc1_b, *fc2_w, *fc2_b;
};

extern "C" void kernel_launch(void* const* d_in, const int* in_sizes, int n_in,
                              void* d_out, int out_size, void* d_ws, size_t ws_size,
                              hipStream_t stream)
{
  (void)in_sizes; (void)n_in; (void)out_size; (void)ws_size;
  const float* xin   = (const float*)d_in[0];
  const int*   cids  = (const int*)  d_in[1];
  const float* convw = (const float*)d_in[2];
  const float* convb = (const float*)d_in[3];
  const float* cls   = (const float*)d_in[4];
  const float* pos   = (const float*)d_in[5];
  const float* sie   = (const float*)d_in[6];
  float* out = (float*)d_out;

  constexpr int SMEM = 4 * 16384 * 2;   // 131072 bytes
  static bool attr_done = [] {
    (void)hipFuncSetAttribute(reinterpret_cast<const void*>(&gemm4p<false, false, bf16>),
                              hipFuncAttributeMaxDynamicSharedMemorySize, SMEM);
    (void)hipFuncSetAttribute(reinterpret_cast<const void*>(&gemm4p<false, true, float>),
                              hipFuncAttributeMaxDynamicSharedMemorySize, SMEM);
    (void)hipFuncSetAttribute(reinterpret_cast<const void*>(&gemm4p<true, false, bf16>),
                              hipFuncAttributeMaxDynamicSharedMemorySize, SMEM);
    return true;
  }();
  (void)attr_done;

  // workspace layout (bytes)
  char* ws = (char*)d_ws;
  bf16*  qkvT = (bf16*)(ws + 0);            // 2304x768 bf16 (also convw_bf slot)
  bf16*  projT = (bf16*)(ws + 3538944);     // 768x768
  bf16*  fc1T = (bf16*)(ws + 4718592);      // 3072x768
  bf16*  fc2T = (bf16*)(ws + 9437184);      // 768x3072
  float* tA   = (float*)(ws + 14155776);    // 13504x768 f32
  float* tB   = (float*)(ws + 55640064);    // 13568x768 f32
  bf16*  hb   = (bf16*)(ws + 97320960);     // 13568x768 bf16
  bf16*  big  = (bf16*)(ws + 118161408);    // qkv / mlp-mid / im2col (79.5MB)
  bf16*  ao   = (bf16*)(ws + 201523200);    // 13568x768 bf16

  dim3 blk(256);

  auto apply_block = [&](float* xbuf, const BlkP& p, int nb, int ntok_) {
    const int M = nb * ntok_;
    const int gm = (M + 255) / 256;
    transpose4_k<<<dim3(6912), blk, 0, stream>>>(
        p.qkv_w, p.proj_w, p.fc1_w, p.fc2_w, qkvT, projT, fc1T, fc2T);
    ln_kernel<<<dim3((M + 3) / 4), blk, 0, stream>>>(xbuf, p.ln1_g, p.ln1_b, hb, M);
    gemm4p<false, false, bf16><<<dim3(gm * 9), dim3(512), SMEM, stream>>>(
        hb, qkvT, p.qkv_b, nullptr, big, M, 2304, 768, 9);
    if (ntok_ == NTOK)
      attn_kernel<14><<<dim3(nb, NHEAD), blk, 0, stream>>>(big, ao, ntok_);
    else
      attn_kernel<4><<<dim3(nb, NHEAD), blk, 0, stream>>>(big, ao, ntok_);
    gemm4p<false, true, float><<<dim3(gm * 3), dim3(512), SMEM, stream>>>(
        ao, projT, p.proj_b, xbuf, xbuf, M, 768, 768, 3);
    ln_kernel<<<dim3((M + 3) / 4), blk, 0, stream>>>(xbuf, p.ln2_g, p.ln2_b, hb, M);
    gemm4p<true, false, bf16><<<dim3(gm * 12), dim3(512), SMEM, stream>>>(
        hb, fc1T, p.fc1_b, nullptr, big, M, 3072, 768, 12);
    gemm4p<false, true, float><<<dim3(gm * 3), dim3(512), SMEM, stream>>>(
        big, fc2T, p.fc2_b, xbuf, xbuf, M, 768, 3072, 3);
  };

  // 1) patch embed: im2col -> GEMM(conv) -> assemble
  {
    int total = 13440 * 768;
    im2col_kernel<<<dim3((total + 255) / 256), blk, 0, stream>>>(xin, big);
    int nw = 768 * 768;
    cast_kernel<<<dim3((nw + 255) / 256), blk, 0, stream>>>(convw, qkvT, nw);
    gemm4p<false, false, bf16><<<dim3(53 * 3), dim3(512), SMEM, stream>>>(
        big, qkvT, convb, nullptr, ao, 13440, 768, 768, 3);
    total = 13504 * 768;
    assemble_kernel<<<dim3((total + 255) / 256), blk, 0, stream>>>(ao, cls, pos, sie, cids, tA);
  }

  // 2) 11 stacked blocks (lead-dim DEPTH params)
  const float* bp[12];
  for (int i = 0; i < 12; ++i) bp[i] = (const float*)d_in[7 + i];
  for (int dd = 0; dd < DEPTH; ++dd) {
    BlkP p;
    p.ln1_g = bp[0] + dd * 768;                p.ln1_b = bp[1] + dd * 768;
    p.qkv_w = bp[2] + (size_t)dd * 768 * 2304; p.qkv_b = bp[3] + dd * 2304;
    p.proj_w = bp[4] + (size_t)dd * 768 * 768; p.proj_b = bp[5] + dd * 768;
    p.ln2_g = bp[6] + dd * 768;                p.ln2_b = bp[7] + dd * 768;
    p.fc1_w = bp[8] + (size_t)dd * 768 * 3072; p.fc1_b = bp[9] + dd * 3072;
    p.fc2_w = bp[10] + (size_t)dd * 3072 * 768; p.fc2_b = bp[11] + dd * 768;
    apply_block(tA, p, 64, NTOK);
  }

  // 3) b1 branch: f0 = LN(block(t))[:,0]
  (void)hipMemcpyAsync(tB, tA, (size_t)13504 * 768 * 4, hipMemcpyDeviceToDevice, stream);
  {
    BlkP p;
    p.ln1_g = (const float*)d_in[19]; p.ln1_b = (const float*)d_in[20];
    p.qkv_w = (const float*)d_in[21]; p.qkv_b = (const float*)d_in[22];
    p.proj_w = (const float*)d_in[23]; p.proj_b = (const float*)d_in[24];
    p.ln2_g = (const float*)d_in[25]; p.ln2_b = (const float*)d_in[26];
    p.fc1_w = (const float*)d_in[27]; p.fc1_b = (const float*)d_in[28];
    p.fc2_w = (const float*)d_in[29]; p.fc2_b = (const float*)d_in[30];
    apply_block(tB, p, 64, NTOK);
    ln_head_kernel<<<dim3(16), blk, 0, stream>>>(
        tB, NTOK, (const float*)d_in[31], (const float*)d_in[32], out, 64, 0);
  }

  // 4) b2 branch: 4 shuffled segments batched as 256 sequences of 53 tokens
  {
    int total = 256 * 53 * 768;
    gather_kernel<<<dim3((total + 255) / 256), blk, 0, stream>>>(tA, tB);
    BlkP p;
    p.ln1_g = (const float*)d_in[33]; p.ln1_b = (const float*)d_in[34];
    p.qkv_w = (const float*)d_in[35]; p.qkv_b = (const float*)d_in[36];
    p.proj_w = (const float*)d_in[37]; p.proj_b = (const float*)d_in[38];
    p.ln2_g = (const float*)d_in[39]; p.ln2_b = (const float*)d_in[40];
    p.fc1_w = (const float*)d_in[41]; p.fc1_b = (const float*)d_in[42];
    p.fc2_w = (const float*)d_in[43]; p.fc2_b = (const float*)d_in[44];
    apply_block(tB, p, 256, 53);
    ln_head_kernel<<<dim3(64), blk, 0, stream>>>(
        tB, 53, (const float*)d_in[45], (const float*)d_in[46], out, 256, 1);
  }
}

// Round 8
// 6583.583 us; speedup vs baseline: 1.1348x; 1.0014x over previous
//
#include <hip/hip_runtime.h>
#include <hip/hip_bf16.h>
#include <cstdint>
#include <cstddef>
#include <math.h>

using bf16 = __hip_bfloat16;
typedef __bf16 bf16x8 __attribute__((ext_vector_type(8)));
typedef float f32x4 __attribute__((ext_vector_type(4)));

// ---------------- constants ----------------
static constexpr int NHEAD = 12;
static constexpr int NTOK  = 211;   // 210 patches + cls
static constexpr int DEPTH = 11;

// ---------------- global->LDS direct load ----------------
static __device__ __forceinline__ void gload_lds16(const bf16* g, bf16* lds) {
  __builtin_amdgcn_global_load_lds(
      (const __attribute__((address_space(1))) uint32_t*)g,
      (__attribute__((address_space(3))) uint32_t*)lds,
      16, 0, 0);
}

#define SCHED_FENCE() __builtin_amdgcn_sched_barrier(0)
// single barrier per phase: each wave certifies its own ds_reads (lgkmcnt(0))
// BEFORE crossing, so post-barrier stage-writes can never overtake a reader.
#define SYNC_PHASE() do { SCHED_FENCE(); \
  asm volatile("s_waitcnt lgkmcnt(0)" ::: "memory"); SCHED_FENCE(); \
  __builtin_amdgcn_s_barrier(); asm volatile("" ::: "memory"); SCHED_FENCE(); } while (0)

__device__ __forceinline__ float gelu_f(float x) {
  float u = x * (0.7978845608f + 0.0356774081f * x * x);
  float t = 1.f - 2.f / (__expf(2.f * u) + 1.f);
  return 0.5f * x * (1.f + t);
}

static __device__ __forceinline__ unsigned short bf16_bits(float x) {
  return __builtin_bit_cast(unsigned short, __float2bfloat16(x));
}

// ---------------- 256x256 K-half-pipelined TN GEMM ----------------
// As round 7 (ring-4 K-half slots, depth-3 prefetch, vmcnt-counted certify,
// 2-way-free XOR swizzle) but ONE barrier per phase (4/K-tile, was 8):
// phase = { stage ; ds_reads ; [vmcnt cert] ; lgkmcnt(0) ; barrier ; 16 MFMA }.
// Race audit: slot written at phase p was last READ at phase p-2; every wave
// crossing barrier p-1 had lgkmcnt(0) => those reads are complete before any
// wave can issue phase-p stage writes. Certify-vmcnt sits pre-barrier, so the
// barrier that publishes LDS data also publishes load completion.
template <bool GELU, bool RES, typename CT>
__global__ __launch_bounds__(512, 2) void gemm4p(
    const bf16* __restrict__ A, const bf16* __restrict__ Bt,
    const float* __restrict__ bias, const float* __restrict__ res,
    CT* __restrict__ C, int M, int N, int K, int gn)
{
  extern __shared__ bf16 lds[];     // 4 * 16384 elems = 128 KB

  const int tid = threadIdx.x;
  const int w = tid >> 6;
  const int l = tid & 63;
  const int lr = l & 15, lg = l >> 4;
  const int wm = w >> 2, wn = w & 3;       // wave: rows wm*128, cols wn*64

  // bijective XCD swizzle (m204), N-fastest tile order
  const int nwg = gridDim.x;
  const int lin = blockIdx.x;
  const int q = nwg >> 3, r = nwg & 7;
  const int xcd = lin & 7, pos = lin >> 3;
  const int wg = (xcd < r ? xcd * (q + 1) : r * (q + 1) + (xcd - r) * q) + pos;
  const int bm0 = (wg / gn) * 256;
  const int bn0 = (wg % gn) * 256;

  f32x4 acc[8][4];
#pragma unroll
  for (int i = 0; i < 8; ++i)
#pragma unroll
    for (int j = 0; j < 4; ++j) acc[i][j] = f32x4{0.f, 0.f, 0.f, 0.f};

  size_t aof[2], bof[2]; int adst[2], bdst[2];
#pragma unroll
  for (int j = 0; j < 2; ++j) {
    const int c = j * 512 + tid;
    const int row = c >> 2;
    const int ch = (c & 3) ^ ((row >> 1) & 3);
    int ar = bm0 + row; if (ar >= M) ar = M - 1;
    aof[j] = (size_t)ar * K + ch * 8;
    bof[j] = (size_t)(bn0 + row) * K + ch * 8;
    adst[j] = c * 8;
    bdst[j] = 8192 + c * 8;
  }

  const int nt = K >> 6;
  const int nh = nt * 2;

  auto stA = [&](int h) {
    bf16* s = lds + (h & 3) * 16384; const size_t ko = (size_t)h * 32;
    gload_lds16(A + aof[0] + ko, s + adst[0]);
    gload_lds16(A + aof[1] + ko, s + adst[1]);
  };
  auto stB = [&](int h) {
    bf16* s = lds + (h & 3) * 16384; const size_t ko = (size_t)h * 32;
    gload_lds16(Bt + bof[0] + ko, s + bdst[0]);
    gload_lds16(Bt + bof[1] + ko, s + bdst[1]);
  };

  // ---- prologue: halves 0,1,2 in flight; certify half 0 ----
  stA(0); stB(0); stA(1); stB(1); stA(2); stB(2);
  asm volatile("s_waitcnt vmcnt(8)" ::: "memory");
  SCHED_FENCE();
  __builtin_amdgcn_s_barrier();
  asm volatile("" ::: "memory");
  SCHED_FENCE();

  const int swz = (lg ^ ((lr >> 1) & 3)) * 8;
  const int arow = wm * 128 + lr;
  const int brow = wn * 64 + lr;

  for (int T = 0; T < nt; ++T) {
    const bf16* s0 = lds + ((2 * T) & 3) * 16384;
    const bf16* s1 = lds + ((2 * T + 1) & 3) * 16384;
    const bool pfa = (2 * T + 2 < nh);
    const bool pf0 = (2 * T + 3 < nh);
    const bool pf1 = (2 * T + 4 < nh);
    bf16x8 bv[4], af[4];

    // ---- p0: half 2T, mi 0-3 ----
    if (pf0) stA(2 * T + 3);
#pragma unroll
    for (int ni = 0; ni < 4; ++ni)
      bv[ni] = *(const bf16x8*)(s0 + 8192 + (brow + ni * 16) * 32 + swz);
#pragma unroll
    for (int mi = 0; mi < 4; ++mi)
      af[mi] = *(const bf16x8*)(s0 + (arow + mi * 16) * 32 + swz);
    SYNC_PHASE();
    __builtin_amdgcn_s_setprio(1);
#pragma unroll
    for (int mi = 0; mi < 4; ++mi)
#pragma unroll
      for (int ni = 0; ni < 4; ++ni)
        acc[mi][ni] = __builtin_amdgcn_mfma_f32_16x16x32_bf16(af[mi], bv[ni], acc[mi][ni], 0, 0, 0);
    __builtin_amdgcn_s_setprio(0);

    // ---- p1: half 2T, mi 4-7 (bv reused) ----
    if (pf0) stB(2 * T + 3);
#pragma unroll
    for (int mi = 0; mi < 4; ++mi)
      af[mi] = *(const bf16x8*)(s0 + (arow + 64 + mi * 16) * 32 + swz);
    // certify half 2T+1 (read at p2): newer loads = half 2T+2 (pfa) + 2T+3 (pf0)
    if (pfa && pf0)      { asm volatile("s_waitcnt vmcnt(8)" ::: "memory"); }
    else if (pfa)        { asm volatile("s_waitcnt vmcnt(4)" ::: "memory"); }
    else                 { asm volatile("s_waitcnt vmcnt(0)" ::: "memory"); }
    SYNC_PHASE();
    __builtin_amdgcn_s_setprio(1);
#pragma unroll
    for (int mi = 0; mi < 4; ++mi)
#pragma unroll
      for (int ni = 0; ni < 4; ++ni)
        acc[4 + mi][ni] = __builtin_amdgcn_mfma_f32_16x16x32_bf16(af[mi], bv[ni], acc[4 + mi][ni], 0, 0, 0);
    __builtin_amdgcn_s_setprio(0);

    // ---- p2: half 2T+1, mi 0-3 ----
    if (pf1) stA(2 * T + 4);
#pragma unroll
    for (int ni = 0; ni < 4; ++ni)
      bv[ni] = *(const bf16x8*)(s1 + 8192 + (brow + ni * 16) * 32 + swz);
#pragma unroll
    for (int mi = 0; mi < 4; ++mi)
      af[mi] = *(const bf16x8*)(s1 + (arow + mi * 16) * 32 + swz);
    SYNC_PHASE();
    __builtin_amdgcn_s_setprio(1);
#pragma unroll
    for (int mi = 0; mi < 4; ++mi)
#pragma unroll
      for (int ni = 0; ni < 4; ++ni)
        acc[mi][ni] = __builtin_amdgcn_mfma_f32_16x16x32_bf16(af[mi], bv[ni], acc[mi][ni], 0, 0, 0);
    __builtin_amdgcn_s_setprio(0);

    // ---- p3: half 2T+1, mi 4-7 ----
    if (pf1) stB(2 * T + 4);
#pragma unroll
    for (int mi = 0; mi < 4; ++mi)
      af[mi] = *(const bf16x8*)(s1 + (arow + 64 + mi * 16) * 32 + swz);
    if (pfa) {
      // certify half 2T+2 (read at next tile's p0): newer = 2T+3, 2T+4
      if (pf0 && pf1)    { asm volatile("s_waitcnt vmcnt(8)" ::: "memory"); }
      else if (pf0)      { asm volatile("s_waitcnt vmcnt(4)" ::: "memory"); }
      else               { asm volatile("s_waitcnt vmcnt(0)" ::: "memory"); }
    }
    SYNC_PHASE();
    __builtin_amdgcn_s_setprio(1);
#pragma unroll
    for (int mi = 0; mi < 4; ++mi)
#pragma unroll
      for (int ni = 0; ni < 4; ++ni)
        acc[4 + mi][ni] = __builtin_amdgcn_mfma_f32_16x16x32_bf16(af[mi], bv[ni], acc[4 + mi][ni], 0, 0, 0);
    __builtin_amdgcn_s_setprio(0);
  }

  // ---- epilogue ----
#pragma unroll
  for (int mi = 0; mi < 8; ++mi) {
#pragma unroll
    for (int ni = 0; ni < 4; ++ni) {
      const int col = bn0 + wn * 64 + ni * 16 + lr;
      const float bvl = bias[col];
#pragma unroll
      for (int r2 = 0; r2 < 4; ++r2) {
        const int row = bm0 + wm * 128 + mi * 16 + lg * 4 + r2;
        if (row < M) {
          float v = acc[mi][ni][r2] + bvl;
          if constexpr (GELU) v = gelu_f(v);
          if constexpr (RES) v += res[(size_t)row * N + col];
          if constexpr (sizeof(CT) == 4) {
            C[(size_t)row * N + col] = v;
          } else {
            C[(size_t)row * N + col] = __float2bfloat16(v);
          }
        }
      }
    }
  }
}

// ---------------- V transpose: qkv V-slice -> vT[bb,h][d][tok_padded] ----------------
__global__ __launch_bounds__(256) void vtrans_kernel(
    const bf16* __restrict__ qkv, bf16* __restrict__ vT, int ntok, int pad)
{
  __shared__ unsigned short t[224 * 65];
  const int bb = blockIdx.x, h = blockIdx.y;
  const unsigned short* src = (const unsigned short*)qkv + (size_t)bb * ntok * 2304 + 1536 + h * 64;
  for (int idx = threadIdx.x; idx < ntok * 64; idx += 256) {
    int tok = idx >> 6, d = idx & 63;
    t[tok * 65 + d] = src[(size_t)tok * 2304 + d];
  }
  __syncthreads();
  unsigned short* dst = (unsigned short*)vT + (size_t)(bb * 12 + h) * 64 * pad;
  for (int idx = threadIdx.x; idx < 64 * ntok; idx += 256) {
    int d = idx / ntok, tok = idx - d * ntok;
    dst[(size_t)d * pad + tok] = t[tok * 65 + d];
  }
}

// ---------------- fused attention: one block per (bb, head) ----------------
template <int NKF>  // NKF = padded token count / 16
__global__ __launch_bounds__(256) void attn_kernel(
    const bf16* __restrict__ qkv, const bf16* __restrict__ vT,
    bf16* __restrict__ ao, int ntok, int pad)
{
  constexpr int NPAD = NKF * 16;
  __shared__ bf16 Pl[4][16][NPAD];
  const int bb = blockIdx.x;
  const int h = blockIdx.y;
  const int tid = threadIdx.x;
  const int w = tid >> 6, l = tid & 63;
  const int lr = l & 15, lg = l >> 4;
  const __bf16* base = reinterpret_cast<const __bf16*>(qkv) + (size_t)bb * ntok * 2304 + h * 64;
  const __bf16* vt = reinterpret_cast<const __bf16*>(vT) + (size_t)(bb * 12 + h) * 64 * pad;

  for (int qt = w; qt < NKF; qt += 4) {
    int qrow = qt * 16 + lr; if (qrow >= ntok) qrow = ntok - 1;
    const __bf16* qp = base + (size_t)qrow * 2304 + lg * 8;
    const bf16x8 qf0 = *reinterpret_cast<const bf16x8*>(qp);
    const bf16x8 qf1 = *reinterpret_cast<const bf16x8*>(qp + 32);

    f32x4 s[NKF];
#pragma unroll
    for (int kf = 0; kf < NKF; ++kf) {
      int krow = kf * 16 + lr; if (krow >= ntok) krow = ntok - 1;
      const __bf16* kp = base + (size_t)krow * 2304 + 768 + lg * 8;
      f32x4 a = f32x4{0.f, 0.f, 0.f, 0.f};
      a = __builtin_amdgcn_mfma_f32_16x16x32_bf16(qf0, *reinterpret_cast<const bf16x8*>(kp), a, 0, 0, 0);
      a = __builtin_amdgcn_mfma_f32_16x16x32_bf16(qf1, *reinterpret_cast<const bf16x8*>(kp + 32), a, 0, 0, 0);
      s[kf] = a;
    }

    float rs[4];
#pragma unroll
    for (int r = 0; r < 4; ++r) {
      float mx = -1e30f;
#pragma unroll
      for (int kf = 0; kf < NKF; ++kf)
        if (kf * 16 + lr < ntok) mx = fmaxf(mx, s[kf][r]);
#pragma unroll
      for (int d = 1; d < 16; d <<= 1) mx = fmaxf(mx, __shfl_xor(mx, d));
      float sum = 0.f;
#pragma unroll
      for (int kf = 0; kf < NKF; ++kf) {
        float p = 0.f;
        if (kf * 16 + lr < ntok) p = __expf((s[kf][r] - mx) * 0.125f);
        sum += p;
        Pl[w][lg * 4 + r][kf * 16 + lr] = __float2bfloat16(p);
      }
#pragma unroll
      for (int d = 1; d < 16; d <<= 1) sum += __shfl_xor(sum, d);
      rs[r] = sum;
    }
    __builtin_amdgcn_s_waitcnt(0);  // lgkm: Pl writes visible to this wave

    f32x4 o[4];
#pragma unroll
    for (int ni = 0; ni < 4; ++ni) o[ni] = f32x4{0.f, 0.f, 0.f, 0.f};
#pragma unroll
    for (int ks = 0; ks < NPAD / 32; ++ks) {
      const bf16x8 pa = *reinterpret_cast<const bf16x8*>(&Pl[w][lr][ks * 32 + lg * 8]);
#pragma unroll
      for (int ni = 0; ni < 4; ++ni) {
        const bf16x8 vb = *reinterpret_cast<const bf16x8*>(
            vt + (size_t)(ni * 16 + lr) * pad + ks * 32 + lg * 8);
        o[ni] = __builtin_amdgcn_mfma_f32_16x16x32_bf16(pa, vb, o[ni], 0, 0, 0);
      }
    }
#pragma unroll
    for (int ni = 0; ni < 4; ++ni)
#pragma unroll
      for (int r = 0; r < 4; ++r) {
        int qq = qt * 16 + lg * 4 + r;
        if (qq < ntok) {
          float val = o[ni][r] / rs[r];
          ao[((size_t)bb * ntok + qq) * 768 + h * 64 + ni * 16 + lr] = __float2bfloat16(val);
        }
      }
  }
}

// ---------------- layernorm: f32 in -> bf16 out, one wave per row ----------------
__global__ __launch_bounds__(256) void ln_kernel(
    const float* __restrict__ x, const float* __restrict__ g, const float* __restrict__ b,
    bf16* __restrict__ out, int Mrows)
{
  int row = blockIdx.x * 4 + (threadIdx.x >> 6);
  if (row >= Mrows) return;
  int l = threadIdx.x & 63;
  const float4* xr = reinterpret_cast<const float4*>(x + (size_t)row * 768);
  float4 v[3]; float s = 0.f;
#pragma unroll
  for (int i = 0; i < 3; ++i) {
    v[i] = xr[l + i * 64];
    s += v[i].x + v[i].y + v[i].z + v[i].w;
  }
#pragma unroll
  for (int d = 1; d < 64; d <<= 1) s += __shfl_xor(s, d);
  float mean = s * (1.f / 768.f);
  float s2 = 0.f;
#pragma unroll
  for (int i = 0; i < 3; ++i) {
    float a0 = v[i].x - mean, a1 = v[i].y - mean, a2 = v[i].z - mean, a3 = v[i].w - mean;
    s2 += a0 * a0 + a1 * a1 + a2 * a2 + a3 * a3;
  }
#pragma unroll
  for (int d = 1; d < 64; d <<= 1) s2 += __shfl_xor(s2, d);
  float rstd = rsqrtf(s2 * (1.f / 768.f) + 1e-6f);
  const float4* g4 = reinterpret_cast<const float4*>(g);
  const float4* b4 = reinterpret_cast<const float4*>(b);
  unsigned short* orow = reinterpret_cast<unsigned short*>(out + (size_t)row * 768);
#pragma unroll
  for (int i = 0; i < 3; ++i) {
    float4 gg = g4[l + i * 64], bb = b4[l + i * 64];
    ushort4 pk;
    pk.x = bf16_bits((v[i].x - mean) * rstd * gg.x + bb.x);
    pk.y = bf16_bits((v[i].y - mean) * rstd * gg.y + bb.y);
    pk.z = bf16_bits((v[i].z - mean) * rstd * gg.z + bb.z);
    pk.w = bf16_bits((v[i].w - mean) * rstd * gg.w + bb.w);
    *reinterpret_cast<ushort4*>(orow + (l + i * 64) * 4) = pk;
  }
}

// ---------------- head layernorm (row 0 of each sequence) -> output (f32) ----------------
__global__ __launch_bounds__(256) void ln_head_kernel(
    const float* __restrict__ x, int tokstride, const float* __restrict__ g,
    const float* __restrict__ b, float* __restrict__ out, int nbb, int mode)
{
  int bb = blockIdx.x * 4 + (threadIdx.x >> 6);
  if (bb >= nbb) return;
  int l = threadIdx.x & 63;
  const float* xr = x + (size_t)bb * tokstride * 768;
  float v[12]; float s = 0.f;
#pragma unroll
  for (int i = 0; i < 12; ++i) { v[i] = xr[l + i * 64]; s += v[i]; }
#pragma unroll
  for (int d = 1; d < 64; d <<= 1) s += __shfl_xor(s, d);
  float mean = s * (1.f / 768.f);
  float s2 = 0.f;
#pragma unroll
  for (int i = 0; i < 12; ++i) { float t = v[i] - mean; s2 += t * t; }
#pragma unroll
  for (int d = 1; d < 64; d <<= 1) s2 += __shfl_xor(s2, d);
  float rstd = rsqrtf(s2 * (1.f / 768.f) + 1e-6f);
  float scale = mode ? 0.25f : 1.f;
  int b_ = mode ? (bb & 63) : bb;
  int off = mode ? (1 + (bb >> 6)) * 768 : 0;
  float* orow = out + (size_t)b_ * 3840 + off;
#pragma unroll
  for (int i = 0; i < 12; ++i) {
    orow[l + i * 64] = ((v[i] - mean) * rstd * g[l + i * 64] + b[l + i * 64]) * scale;
  }
}

// ---------------- fused 4-matrix weight transpose (R,C) f32 -> (C,R) bf16 ----------------
__global__ __launch_bounds__(256) void transpose4_k(
    const float* __restrict__ w0, const float* __restrict__ w1,
    const float* __restrict__ w2, const float* __restrict__ w3,
    bf16* __restrict__ d0, bf16* __restrict__ d1,
    bf16* __restrict__ d2, bf16* __restrict__ d3)
{
  __shared__ float tile[32][33];
  int id = blockIdx.x;
  const float* in; bf16* out; int R, C, tt;
  if (id < 1728)      { in = w0; out = d0; R = 768;  C = 2304; tt = id; }
  else if (id < 2304) { in = w1; out = d1; R = 768;  C = 768;  tt = id - 1728; }
  else if (id < 4608) { in = w2; out = d2; R = 768;  C = 3072; tt = id - 2304; }
  else                { in = w3; out = d3; R = 3072; C = 768;  tt = id - 4608; }
  const int tc = C >> 5;
  int c0 = (tt % tc) * 32, r0 = (tt / tc) * 32;
  int tx = threadIdx.x & 31, ty = threadIdx.x >> 5;
#pragma unroll
  for (int i = 0; i < 4; ++i) {
    int rr = ty + i * 8;
    tile[rr][tx] = in[(size_t)(r0 + rr) * C + c0 + tx];
  }
  __syncthreads();
#pragma unroll
  for (int i = 0; i < 4; ++i) {
    int c = ty + i * 8;
    out[(size_t)(c0 + c) * R + r0 + tx] = __float2bfloat16(tile[tx][c]);
  }
}

// ---------------- f32 -> bf16 cast ----------------
__global__ void cast_kernel(const float* __restrict__ in, bf16* __restrict__ out, int n)
{
  int idx = blockIdx.x * 256 + threadIdx.x;
  if (idx < n) out[idx] = __float2bfloat16(in[idx]);
}

// ---------------- patch im2col (f32 -> bf16) ----------------
__global__ void im2col_kernel(const float* __restrict__ x, bf16* __restrict__ pm)
{
  int idx = blockIdx.x * 256 + threadIdx.x;
  if (idx >= 13440 * 768) return;
  int k = idx % 768;
  int m = idx / 768;
  int b = m / 210, p = m % 210;
  int py = p / 10, px = p % 10;
  int c = k >> 8, ij = k & 255, i = ij >> 4, j = ij & 15;
  pm[idx] = __float2bfloat16(x[(((size_t)b * 3 + c) * 256 + py * 12 + i) * 128 + px * 12 + j]);
}

// ---------------- assemble t = [cls | patches] + pos + SIE*sie[cid] (f32) ----------------
__global__ void assemble_kernel(
    const bf16* __restrict__ y, const float* __restrict__ cls, const float* __restrict__ pos,
    const float* __restrict__ sie, const int* __restrict__ cids, float* __restrict__ tA)
{
  int idx = blockIdx.x * 256 + threadIdx.x;
  if (idx >= 13504 * 768) return;
  int d = idx % 768;
  int t = (idx / 768) % 211;
  int b = idx / (768 * 211);
  float v = pos[t * 768 + d] + 3.0f * sie[cids[b] * 768 + d];
  if (t == 0) v += cls[d];
  else v += __bfloat162float(y[((size_t)b * 210 + (t - 1)) * 768 + d]);
  tA[idx] = v;
}

// ---------------- gather the 4 shuffled segments into a 256-batch of 53 tokens ----------------
__global__ void gather_kernel(const float* __restrict__ tA, float* __restrict__ tB)
{
  int idx = blockIdx.x * 256 + threadIdx.x;
  if (idx >= 256 * 53 * 768) return;
  int d = idx % 768;
  int jj = (idx / 768) % 53;
  int bb = idx / (768 * 53);
  int i = bb >> 6, b = bb & 63;
  int src;
  if (jj == 0) src = 0;
  else {
    int jx = i * 52 + (jj - 1);
    int mm = (jx & 1) * 105 + (jx >> 1);
    src = (mm < 206) ? (5 + mm) : (1 + (mm - 206));
  }
  tB[idx] = tA[((size_t)b * 211 + src) * 768 + d];
}

// ---------------- host orchestration ----------------
struct BlkP {
  const float *ln1_g, *ln1_b, *qkv_w, *qkv_b, *proj_w, *proj_b;
  const float *ln2_g, *ln2_b, *fc1_w, *fc1_b, *fc2_w, *fc2_b;
};

extern "C" void kernel_launch(void* const* d_in, const int* in_sizes, int n_in,
                              void* d_out, int out_size, void* d_ws, size_t ws_size,
                              hipStream_t stream)
{
  (void)in_sizes; (void)n_in; (void)out_size; (void)ws_size;
  const float* xin   = (const float*)d_in[0];
  const int*   cids  = (const int*)  d_in[1];
  const float* convw = (const float*)d_in[2];
  const float* convb = (const float*)d_in[3];
  const float* cls   = (const float*)d_in[4];
  const float* pos   = (const float*)d_in[5];
  const float* sie   = (const float*)d_in[6];
  float* out = (float*)d_out;

  constexpr int SMEM = 4 * 16384 * 2;   // 131072 bytes
  static bool attr_done = [] {
    (void)hipFuncSetAttribute(reinterpret_cast<const void*>(&gemm4p<false, false, bf16>),
                              hipFuncAttributeMaxDynamicSharedMemorySize, SMEM);
    (void)hipFuncSetAttribute(reinterpret_cast<const void*>(&gemm4p<false, true, float>),
                              hipFuncAttributeMaxDynamicSharedMemorySize, SMEM);
    (void)hipFuncSetAttribute(reinterpret_cast<const void*>(&gemm4p<true, false, bf16>),
                              hipFuncAttributeMaxDynamicSharedMemorySize, SMEM);
    return true;
  }();
  (void)attr_done;

  // workspace layout (bytes)
  char* ws = (char*)d_ws;
  bf16*  qkvT = (bf16*)(ws + 0);            // 2304x768 bf16 (also convw_bf slot)
  bf16*  projT = (bf16*)(ws + 3538944);     // 768x768
  bf16*  fc1T = (bf16*)(ws + 4718592);      // 3072x768
  bf16*  fc2T = (bf16*)(ws + 9437184);      // 768x3072
  float* tA   = (float*)(ws + 14155776);    // 13504x768 f32
  float* tB   = (float*)(ws + 55640064);    // 13568x768 f32
  bf16*  hb   = (bf16*)(ws + 97320960);     // 13568x768 bf16
  bf16*  big  = (bf16*)(ws + 118161408);    // qkv / mlp-mid / im2col (79.5MB)
  bf16*  ao   = (bf16*)(ws + 201523200);    // 13568x768 bf16
  bf16*  vTb  = (bf16*)(ws + 222363648);    // V^T buffer (25.2MB)

  dim3 blk(256);

  auto apply_block = [&](float* xbuf, const BlkP& p, int nb, int ntok_) {
    const int M = nb * ntok_;
    const int gm = (M + 255) / 256;
    const int pad = (ntok_ == NTOK) ? 224 : 64;
    transpose4_k<<<dim3(6912), blk, 0, stream>>>(
        p.qkv_w, p.proj_w, p.fc1_w, p.fc2_w, qkvT, projT, fc1T, fc2T);
    ln_kernel<<<dim3((M + 3) / 4), blk, 0, stream>>>(xbuf, p.ln1_g, p.ln1_b, hb, M);
    gemm4p<false, false, bf16><<<dim3(gm * 9), dim3(512), SMEM, stream>>>(
        hb, qkvT, p.qkv_b, nullptr, big, M, 2304, 768, 9);
    vtrans_kernel<<<dim3(nb, NHEAD), blk, 0, stream>>>(big, vTb, ntok_, pad);
    if (ntok_ == NTOK)
      attn_kernel<14><<<dim3(nb, NHEAD), blk, 0, stream>>>(big, vTb, ao, ntok_, pad);
    else
      attn_kernel<4><<<dim3(nb, NHEAD), blk, 0, stream>>>(big, vTb, ao, ntok_, pad);
    gemm4p<false, true, float><<<dim3(gm * 3), dim3(512), SMEM, stream>>>(
        ao, projT, p.proj_b, xbuf, xbuf, M, 768, 768, 3);
    ln_kernel<<<dim3((M + 3) / 4), blk, 0, stream>>>(xbuf, p.ln2_g, p.ln2_b, hb, M);
    gemm4p<true, false, bf16><<<dim3(gm * 12), dim3(512), SMEM, stream>>>(
        hb, fc1T, p.fc1_b, nullptr, big, M, 3072, 768, 12);
    gemm4p<false, true, float><<<dim3(gm * 3), dim3(512), SMEM, stream>>>(
        big, fc2T, p.fc2_b, xbuf, xbuf, M, 768, 3072, 3);
  };

  // 1) patch embed: im2col -> GEMM(conv) -> assemble
  {
    int total = 13440 * 768;
    im2col_kernel<<<dim3((total + 255) / 256), blk, 0, stream>>>(xin, big);
    int nw = 768 * 768;
    cast_kernel<<<dim3((nw + 255) / 256), blk, 0, stream>>>(convw, qkvT, nw);
    gemm4p<false, false, bf16><<<dim3(53 * 3), dim3(512), SMEM, stream>>>(
        big, qkvT, convb, nullptr, ao, 13440, 768, 768, 3);
    total = 13504 * 768;
    assemble_kernel<<<dim3((total + 255) / 256), blk, 0, stream>>>(ao, cls, pos, sie, cids, tA);
  }

  // 2) 11 stacked blocks (lead-dim DEPTH params)
  const float* bp[12];
  for (int i = 0; i < 12; ++i) bp[i] = (const float*)d_in[7 + i];
  for (int dd = 0; dd < DEPTH; ++dd) {
    BlkP p;
    p.ln1_g = bp[0] + dd * 768;                p.ln1_b = bp[1] + dd * 768;
    p.qkv_w = bp[2] + (size_t)dd * 768 * 2304; p.qkv_b = bp[3] + dd * 2304;
    p.proj_w = bp[4] + (size_t)dd * 768 * 768; p.proj_b = bp[5] + dd * 768;
    p.ln2_g = bp[6] + dd * 768;                p.ln2_b = bp[7] + dd * 768;
    p.fc1_w = bp[8] + (size_t)dd * 768 * 3072; p.fc1_b = bp[9] + dd * 3072;
    p.fc2_w = bp[10] + (size_t)dd * 3072 * 768; p.fc2_b = bp[11] + dd * 768;
    apply_block(tA, p, 64, NTOK);
  }

  // 3) b1 branch: f0 = LN(block(t))[:,0]
  (void)hipMemcpyAsync(tB, tA, (size_t)13504 * 768 * 4, hipMemcpyDeviceToDevice, stream);
  {
    BlkP p;
    p.ln1_g = (const float*)d_in[19]; p.ln1_b = (const float*)d_in[20];
    p.qkv_w = (const float*)d_in[21]; p.qkv_b = (const float*)d_in[22];
    p.proj_w = (const float*)d_in[23]; p.proj_b = (const float*)d_in[24];
    p.ln2_g = (const float*)d_in[25]; p.ln2_b = (const float*)d_in[26];
    p.fc1_w = (const float*)d_in[27]; p.fc1_b = (const float*)d_in[28];
    p.fc2_w = (const float*)d_in[29]; p.fc2_b = (const float*)d_in[30];
    apply_block(tB, p, 64, NTOK);
    ln_head_kernel<<<dim3(16), blk, 0, stream>>>(
        tB, NTOK, (const float*)d_in[31], (const float*)d_in[32], out, 64, 0);
  }

  // 4) b2 branch: 4 shuffled segments batched as 256 sequences of 53 tokens
  {
    int total = 256 * 53 * 768;
    gather_kernel<<<dim3((total + 255) / 256), blk, 0, stream>>>(tA, tB);
    BlkP p;
    p.ln1_g = (const float*)d_in[33]; p.ln1_b = (const float*)d_in[34];
    p.qkv_w = (const float*)d_in[35]; p.qkv_b = (const float*)d_in[36];
    p.proj_w = (const float*)d_in[37]; p.proj_b = (const float*)d_in[38];
    p.ln2_g = (const float*)d_in[39]; p.ln2_b = (const float*)d_in[40];
    p.fc1_w = (const float*)d_in[41]; p.fc1_b = (const float*)d_in[42];
    p.fc2_w = (const float*)d_in[43]; p.fc2_b = (const float*)d_in[44];
    apply_block(tB, p, 256, 53);
    ln_head_kernel<<<dim3(64), blk, 0, stream>>>(
        tB, 53, (const float*)d_in[45], (const float*)d_in[46], out, 256, 1);
  }
}

// Round 9
// 5550.314 us; speedup vs baseline: 1.3460x; 1.1862x over previous
//
#include <hip/hip_runtime.h>
#include <hip/hip_bf16.h>
#include <cstdint>
#include <cstddef>
#include <math.h>

using bf16 = __hip_bfloat16;
typedef __bf16 bf16x8 __attribute__((ext_vector_type(8)));
typedef float f32x4 __attribute__((ext_vector_type(4)));

// ---------------- constants ----------------
static constexpr int NHEAD = 12;
static constexpr int NTOK  = 211;   // 210 patches + cls
static constexpr int DEPTH = 11;

// ---------------- global->LDS direct load ----------------
static __device__ __forceinline__ void gload_lds16(const bf16* g, bf16* lds) {
  __builtin_amdgcn_global_load_lds(
      (const __attribute__((address_space(1))) uint32_t*)g,
      (__attribute__((address_space(3))) uint32_t*)lds,
      16, 0, 0);
}

__device__ __forceinline__ float gelu_f(float x) {
  float u = x * (0.7978845608f + 0.0356774081f * x * x);
  float t = 1.f - 2.f / (__expf(2.f * u) + 1.f);
  return 0.5f * x * (1.f + t);
}

static __device__ __forceinline__ unsigned short bf16_bits(float x) {
  return __builtin_bit_cast(unsigned short, __float2bfloat16(x));
}

// ---------------- m97-style double-buffered TN GEMM (high inter-block TLP) ----------------
// C[M,N] = A[M,K] * Bt[N,K]^T (+bias,+gelu,+residual)
// 128x128 tile, BK=32, 256 thr = 4 waves (2x2), wave owns 64x64 (16 MFMA/iter).
// LDS 32KB: two 16KB buffers (A[128][32]+B[128][32] each). Plain __syncthreads()
// (compiler emits the vmcnt/lgkm drain) -- correctness-proven m97 structure; the
// ~3 blocks/CU of inter-block TLP hides the drain (m114), which the giant-block
// lockstep schedules of rounds 3-8 could not.
// Swizzle: phys chunk = ch ^ ((row>>1)&3) within each 64B row; staging permutes
// the GLOBAL source, frag reads apply the same XOR (2-way = free).
// bf16 epilogue: LDS-bounce (reuse the 32KB) -> coalesced 16B global stores.
template <bool GELU, bool RES, typename CT>
__global__ __launch_bounds__(256) void gemm_db(
    const bf16* __restrict__ A, const bf16* __restrict__ Bt,
    const float* __restrict__ bias, const float* __restrict__ res,
    CT* __restrict__ C, int M, int N, int K, int gn)
{
  __shared__ bf16 sb[2][8192];   // 32 KB total

  const int tid = threadIdx.x;
  const int w = tid >> 6, l = tid & 63;
  const int lr = l & 15, lg = l >> 4;
  const int wr = (w >> 1) * 64, wc = (w & 1) * 64;

  // bijective XCD swizzle (m204), N-fastest tile order
  const int nwg = gridDim.x, lin = blockIdx.x;
  const int q = nwg >> 3, r = nwg & 7;
  const int xcd = lin & 7, pos = lin >> 3;
  const int wg = (xcd < r ? xcd * (q + 1) : r * (q + 1) + (xcd - r) * q) + pos;
  const int bm0 = (wg / gn) * 128, bn0 = (wg % gn) * 128;

  f32x4 acc[4][4];
#pragma unroll
  for (int i = 0; i < 4; ++i)
#pragma unroll
    for (int j = 0; j < 4; ++j) acc[i][j] = f32x4{0.f, 0.f, 0.f, 0.f};

  // staging: 2 A-chunks + 2 B-chunks (16B) per thread per K-step.
  // phys chunk c: row = c>>2, holds logical ch = (c&3) ^ ((row>>1)&3).
  size_t aof[2], bof[2]; int dst[2];
#pragma unroll
  for (int j = 0; j < 2; ++j) {
    const int c = j * 256 + tid;
    const int row = c >> 2;
    const int ch = (c & 3) ^ ((row >> 1) & 3);
    int ar = bm0 + row; if (ar >= M) ar = M - 1;
    aof[j] = (size_t)ar * K + ch * 8;
    bof[j] = (size_t)(bn0 + row) * K + ch * 8;
    dst[j] = c * 8;
  }

  const int nt = K >> 5;

  auto stage = [&](int t) {
    bf16* s = sb[t & 1];
    const size_t ko = (size_t)t * 32;
    gload_lds16(A + aof[0] + ko, s + dst[0]);
    gload_lds16(A + aof[1] + ko, s + dst[1]);
    gload_lds16(Bt + bof[0] + ko, s + 4096 + dst[0]);
    gload_lds16(Bt + bof[1] + ko, s + 4096 + dst[1]);
  };

  stage(0);
  __syncthreads();

  const int swz = (lg ^ ((lr >> 1) & 3)) * 8;

  for (int t = 0; t < nt; ++t) {
    if (t + 1 < nt) stage(t + 1);
    const bf16* As = sb[t & 1];
    const bf16* Bs = As + 4096;
    bf16x8 af[4], bv[4];
#pragma unroll
    for (int mi = 0; mi < 4; ++mi)
      af[mi] = *(const bf16x8*)(As + (wr + mi * 16 + lr) * 32 + swz);
#pragma unroll
    for (int ni = 0; ni < 4; ++ni)
      bv[ni] = *(const bf16x8*)(Bs + (wc + ni * 16 + lr) * 32 + swz);
#pragma unroll
    for (int mi = 0; mi < 4; ++mi)
#pragma unroll
      for (int ni = 0; ni < 4; ++ni)
        acc[mi][ni] = __builtin_amdgcn_mfma_f32_16x16x32_bf16(af[mi], bv[ni], acc[mi][ni], 0, 0, 0);
    __syncthreads();   // drains stage vmcnt + frag lgkm (compiler-inserted)
  }

  if constexpr (sizeof(CT) == 2) {
    // ---- LDS-bounce epilogue: bank-spread XOR, then coalesced 16B stores ----
    char* lb = (char*)sb;     // 32 KB = 128 rows x 256 B
#pragma unroll
    for (int mi = 0; mi < 4; ++mi) {
#pragma unroll
      for (int ni = 0; ni < 4; ++ni) {
        const int cloc = wc + ni * 16 + lr;
        const float bvl = bias[bn0 + cloc];
#pragma unroll
        for (int r2 = 0; r2 < 4; ++r2) {
          const int rowl = wr + mi * 16 + lg * 4 + r2;
          float v = acc[mi][ni][r2] + bvl;
          if constexpr (GELU) v = gelu_f(v);
          *(unsigned short*)(lb + rowl * 256 + ((cloc * 2) ^ (((rowl >> 1) & 6) << 4))) =
              bf16_bits(v);
        }
      }
    }
    __syncthreads();
#pragma unroll
    for (int j = 0; j < 8; ++j) {
      const int flat = j * 256 + tid;          // 2048 chunks of 16B
      const int row = flat >> 4, ch = flat & 15;
      const int grow = bm0 + row;
      if (grow < M) {
        const f32x4 v = *(const f32x4*)(lb + row * 256 + ((ch * 16) ^ (((row >> 1) & 6) << 4)));
        *(f32x4*)((char*)C + ((size_t)grow * N + bn0 + ch * 8) * 2) = v;
      }
    }
  } else {
    // ---- f32-out epilogue (proj/fc2: +residual) ----
#pragma unroll
    for (int mi = 0; mi < 4; ++mi) {
#pragma unroll
      for (int ni = 0; ni < 4; ++ni) {
        const int col = bn0 + wc + ni * 16 + lr;
        const float bvl = bias[col];
#pragma unroll
        for (int r2 = 0; r2 < 4; ++r2) {
          const int row = bm0 + wr + mi * 16 + lg * 4 + r2;
          if (row < M) {
            float v = acc[mi][ni][r2] + bvl;
            if constexpr (GELU) v = gelu_f(v);
            if constexpr (RES) v += res[(size_t)row * N + col];
            C[(size_t)row * N + col] = v;
          }
        }
      }
    }
  }
}

// ---------------- V transpose: qkv V-slice -> vT[bb,h][d][tok_padded] ----------------
__global__ __launch_bounds__(256) void vtrans_kernel(
    const bf16* __restrict__ qkv, bf16* __restrict__ vT, int ntok, int pad)
{
  __shared__ unsigned short t[224 * 65];
  const int bb = blockIdx.x, h = blockIdx.y;
  const unsigned short* src = (const unsigned short*)qkv + (size_t)bb * ntok * 2304 + 1536 + h * 64;
  for (int idx = threadIdx.x; idx < ntok * 64; idx += 256) {
    int tok = idx >> 6, d = idx & 63;
    t[tok * 65 + d] = src[(size_t)tok * 2304 + d];
  }
  __syncthreads();
  unsigned short* dst = (unsigned short*)vT + (size_t)(bb * 12 + h) * 64 * pad;
  for (int idx = threadIdx.x; idx < 64 * ntok; idx += 256) {
    int d = idx / ntok, tok = idx - d * ntok;
    dst[(size_t)d * pad + tok] = t[tok * 65 + d];
  }
}

// ---------------- fused attention: one block per (bb, head) ----------------
template <int NKF>  // NKF = padded token count / 16
__global__ __launch_bounds__(256) void attn_kernel(
    const bf16* __restrict__ qkv, const bf16* __restrict__ vT,
    bf16* __restrict__ ao, int ntok, int pad)
{
  constexpr int NPAD = NKF * 16;
  __shared__ bf16 Pl[4][16][NPAD];
  const int bb = blockIdx.x;
  const int h = blockIdx.y;
  const int tid = threadIdx.x;
  const int w = tid >> 6, l = tid & 63;
  const int lr = l & 15, lg = l >> 4;
  const __bf16* base = reinterpret_cast<const __bf16*>(qkv) + (size_t)bb * ntok * 2304 + h * 64;
  const __bf16* vt = reinterpret_cast<const __bf16*>(vT) + (size_t)(bb * 12 + h) * 64 * pad;

  for (int qt = w; qt < NKF; qt += 4) {
    int qrow = qt * 16 + lr; if (qrow >= ntok) qrow = ntok - 1;
    const __bf16* qp = base + (size_t)qrow * 2304 + lg * 8;
    const bf16x8 qf0 = *reinterpret_cast<const bf16x8*>(qp);
    const bf16x8 qf1 = *reinterpret_cast<const bf16x8*>(qp + 32);

    f32x4 s[NKF];
#pragma unroll
    for (int kf = 0; kf < NKF; ++kf) {
      int krow = kf * 16 + lr; if (krow >= ntok) krow = ntok - 1;
      const __bf16* kp = base + (size_t)krow * 2304 + 768 + lg * 8;
      f32x4 a = f32x4{0.f, 0.f, 0.f, 0.f};
      a = __builtin_amdgcn_mfma_f32_16x16x32_bf16(qf0, *reinterpret_cast<const bf16x8*>(kp), a, 0, 0, 0);
      a = __builtin_amdgcn_mfma_f32_16x16x32_bf16(qf1, *reinterpret_cast<const bf16x8*>(kp + 32), a, 0, 0, 0);
      s[kf] = a;
    }

    float rs[4];
#pragma unroll
    for (int r = 0; r < 4; ++r) {
      float mx = -1e30f;
#pragma unroll
      for (int kf = 0; kf < NKF; ++kf)
        if (kf * 16 + lr < ntok) mx = fmaxf(mx, s[kf][r]);
#pragma unroll
      for (int d = 1; d < 16; d <<= 1) mx = fmaxf(mx, __shfl_xor(mx, d));
      float sum = 0.f;
#pragma unroll
      for (int kf = 0; kf < NKF; ++kf) {
        float p = 0.f;
        if (kf * 16 + lr < ntok) p = __expf((s[kf][r] - mx) * 0.125f);
        sum += p;
        Pl[w][lg * 4 + r][kf * 16 + lr] = __float2bfloat16(p);
      }
#pragma unroll
      for (int d = 1; d < 16; d <<= 1) sum += __shfl_xor(sum, d);
      rs[r] = sum;
    }
    __builtin_amdgcn_s_waitcnt(0);  // lgkm: Pl writes visible to this wave

    f32x4 o[4];
#pragma unroll
    for (int ni = 0; ni < 4; ++ni) o[ni] = f32x4{0.f, 0.f, 0.f, 0.f};
#pragma unroll
    for (int ks = 0; ks < NPAD / 32; ++ks) {
      const bf16x8 pa = *reinterpret_cast<const bf16x8*>(&Pl[w][lr][ks * 32 + lg * 8]);
#pragma unroll
      for (int ni = 0; ni < 4; ++ni) {
        const bf16x8 vb = *reinterpret_cast<const bf16x8*>(
            vt + (size_t)(ni * 16 + lr) * pad + ks * 32 + lg * 8);
        o[ni] = __builtin_amdgcn_mfma_f32_16x16x32_bf16(pa, vb, o[ni], 0, 0, 0);
      }
    }
#pragma unroll
    for (int ni = 0; ni < 4; ++ni)
#pragma unroll
      for (int r = 0; r < 4; ++r) {
        int qq = qt * 16 + lg * 4 + r;
        if (qq < ntok) {
          float val = o[ni][r] / rs[r];
          ao[((size_t)bb * ntok + qq) * 768 + h * 64 + ni * 16 + lr] = __float2bfloat16(val);
        }
      }
  }
}

// ---------------- layernorm: f32 in -> bf16 out, one wave per row ----------------
__global__ __launch_bounds__(256) void ln_kernel(
    const float* __restrict__ x, const float* __restrict__ g, const float* __restrict__ b,
    bf16* __restrict__ out, int Mrows)
{
  int row = blockIdx.x * 4 + (threadIdx.x >> 6);
  if (row >= Mrows) return;
  int l = threadIdx.x & 63;
  const float4* xr = reinterpret_cast<const float4*>(x + (size_t)row * 768);
  float4 v[3]; float s = 0.f;
#pragma unroll
  for (int i = 0; i < 3; ++i) {
    v[i] = xr[l + i * 64];
    s += v[i].x + v[i].y + v[i].z + v[i].w;
  }
#pragma unroll
  for (int d = 1; d < 64; d <<= 1) s += __shfl_xor(s, d);
  float mean = s * (1.f / 768.f);
  float s2 = 0.f;
#pragma unroll
  for (int i = 0; i < 3; ++i) {
    float a0 = v[i].x - mean, a1 = v[i].y - mean, a2 = v[i].z - mean, a3 = v[i].w - mean;
    s2 += a0 * a0 + a1 * a1 + a2 * a2 + a3 * a3;
  }
#pragma unroll
  for (int d = 1; d < 64; d <<= 1) s2 += __shfl_xor(s2, d);
  float rstd = rsqrtf(s2 * (1.f / 768.f) + 1e-6f);
  const float4* g4 = reinterpret_cast<const float4*>(g);
  const float4* b4 = reinterpret_cast<const float4*>(b);
  unsigned short* orow = reinterpret_cast<unsigned short*>(out + (size_t)row * 768);
#pragma unroll
  for (int i = 0; i < 3; ++i) {
    float4 gg = g4[l + i * 64], bb = b4[l + i * 64];
    ushort4 pk;
    pk.x = bf16_bits((v[i].x - mean) * rstd * gg.x + bb.x);
    pk.y = bf16_bits((v[i].y - mean) * rstd * gg.y + bb.y);
    pk.z = bf16_bits((v[i].z - mean) * rstd * gg.z + bb.z);
    pk.w = bf16_bits((v[i].w - mean) * rstd * gg.w + bb.w);
    *reinterpret_cast<ushort4*>(orow + (l + i * 64) * 4) = pk;
  }
}

// ---------------- head layernorm (row 0 of each sequence) -> output (f32) ----------------
__global__ __launch_bounds__(256) void ln_head_kernel(
    const float* __restrict__ x, int tokstride, const float* __restrict__ g,
    const float* __restrict__ b, float* __restrict__ out, int nbb, int mode)
{
  int bb = blockIdx.x * 4 + (threadIdx.x >> 6);
  if (bb >= nbb) return;
  int l = threadIdx.x & 63;
  const float* xr = x + (size_t)bb * tokstride * 768;
  float v[12]; float s = 0.f;
#pragma unroll
  for (int i = 0; i < 12; ++i) { v[i] = xr[l + i * 64]; s += v[i]; }
#pragma unroll
  for (int d = 1; d < 64; d <<= 1) s += __shfl_xor(s, d);
  float mean = s * (1.f / 768.f);
  float s2 = 0.f;
#pragma unroll
  for (int i = 0; i < 12; ++i) { float t = v[i] - mean; s2 += t * t; }
#pragma unroll
  for (int d = 1; d < 64; d <<= 1) s2 += __shfl_xor(s2, d);
  float rstd = rsqrtf(s2 * (1.f / 768.f) + 1e-6f);
  float scale = mode ? 0.25f : 1.f;
  int b_ = mode ? (bb & 63) : bb;
  int off = mode ? (1 + (bb >> 6)) * 768 : 0;
  float* orow = out + (size_t)b_ * 3840 + off;
#pragma unroll
  for (int i = 0; i < 12; ++i) {
    orow[l + i * 64] = ((v[i] - mean) * rstd * g[l + i * 64] + b[l + i * 64]) * scale;
  }
}

// ---------------- fused 4-matrix weight transpose (R,C) f32 -> (C,R) bf16 ----------------
__global__ __launch_bounds__(256) void transpose4_k(
    const float* __restrict__ w0, const float* __restrict__ w1,
    const float* __restrict__ w2, const float* __restrict__ w3,
    bf16* __restrict__ d0, bf16* __restrict__ d1,
    bf16* __restrict__ d2, bf16* __restrict__ d3)
{
  __shared__ float tile[32][33];
  int id = blockIdx.x;
  const float* in; bf16* out; int R, C, tt;
  if (id < 1728)      { in = w0; out = d0; R = 768;  C = 2304; tt = id; }
  else if (id < 2304) { in = w1; out = d1; R = 768;  C = 768;  tt = id - 1728; }
  else if (id < 4608) { in = w2; out = d2; R = 768;  C = 3072; tt = id - 2304; }
  else                { in = w3; out = d3; R = 3072; C = 768;  tt = id - 4608; }
  const int tc = C >> 5;
  int c0 = (tt % tc) * 32, r0 = (tt / tc) * 32;
  int tx = threadIdx.x & 31, ty = threadIdx.x >> 5;
#pragma unroll
  for (int i = 0; i < 4; ++i) {
    int rr = ty + i * 8;
    tile[rr][tx] = in[(size_t)(r0 + rr) * C + c0 + tx];
  }
  __syncthreads();
#pragma unroll
  for (int i = 0; i < 4; ++i) {
    int c = ty + i * 8;
    out[(size_t)(c0 + c) * R + r0 + tx] = __float2bfloat16(tile[tx][c]);
  }
}

// ---------------- f32 -> bf16 cast ----------------
__global__ void cast_kernel(const float* __restrict__ in, bf16* __restrict__ out, int n)
{
  int idx = blockIdx.x * 256 + threadIdx.x;
  if (idx < n) out[idx] = __float2bfloat16(in[idx]);
}

// ---------------- patch im2col (f32 -> bf16) ----------------
__global__ void im2col_kernel(const float* __restrict__ x, bf16* __restrict__ pm)
{
  int idx = blockIdx.x * 256 + threadIdx.x;
  if (idx >= 13440 * 768) return;
  int k = idx % 768;
  int m = idx / 768;
  int b = m / 210, p = m % 210;
  int py = p / 10, px = p % 10;
  int c = k >> 8, ij = k & 255, i = ij >> 4, j = ij & 15;
  pm[idx] = __float2bfloat16(x[(((size_t)b * 3 + c) * 256 + py * 12 + i) * 128 + px * 12 + j]);
}

// ---------------- assemble t = [cls | patches] + pos + SIE*sie[cid] (f32) ----------------
__global__ void assemble_kernel(
    const bf16* __restrict__ y, const float* __restrict__ cls, const float* __restrict__ pos,
    const float* __restrict__ sie, const int* __restrict__ cids, float* __restrict__ tA)
{
  int idx = blockIdx.x * 256 + threadIdx.x;
  if (idx >= 13504 * 768) return;
  int d = idx % 768;
  int t = (idx / 768) % 211;
  int b = idx / (768 * 211);
  float v = pos[t * 768 + d] + 3.0f * sie[cids[b] * 768 + d];
  if (t == 0) v += cls[d];
  else v += __bfloat162float(y[((size_t)b * 210 + (t - 1)) * 768 + d]);
  tA[idx] = v;
}

// ---------------- gather the 4 shuffled segments into a 256-batch of 53 tokens ----------------
__global__ void gather_kernel(const float* __restrict__ tA, float* __restrict__ tB)
{
  int idx = blockIdx.x * 256 + threadIdx.x;
  if (idx >= 256 * 53 * 768) return;
  int d = idx % 768;
  int jj = (idx / 768) % 53;
  int bb = idx / (768 * 53);
  int i = bb >> 6, b = bb & 63;
  int src;
  if (jj == 0) src = 0;
  else {
    int jx = i * 52 + (jj - 1);
    int mm = (jx & 1) * 105 + (jx >> 1);
    src = (mm < 206) ? (5 + mm) : (1 + (mm - 206));
  }
  tB[idx] = tA[((size_t)b * 211 + src) * 768 + d];
}

// ---------------- host orchestration ----------------
struct BlkP {
  const float *ln1_g, *ln1_b, *qkv_w, *qkv_b, *proj_w, *proj_b;
  const float *ln2_g, *ln2_b, *fc1_w, *fc1_b, *fc2_w, *fc2_b;
};

extern "C" void kernel_launch(void* const* d_in, const int* in_sizes, int n_in,
                              void* d_out, int out_size, void* d_ws, size_t ws_size,
                              hipStream_t stream)
{
  (void)in_sizes; (void)n_in; (void)out_size; (void)ws_size;
  const float* xin   = (const float*)d_in[0];
  const int*   cids  = (const int*)  d_in[1];
  const float* convw = (const float*)d_in[2];
  const float* convb = (const float*)d_in[3];
  const float* cls   = (const float*)d_in[4];
  const float* pos   = (const float*)d_in[5];
  const float* sie   = (const float*)d_in[6];
  float* out = (float*)d_out;

  // workspace layout (bytes)
  char* ws = (char*)d_ws;
  bf16*  qkvT = (bf16*)(ws + 0);            // 2304x768 bf16 (also convw_bf slot)
  bf16*  projT = (bf16*)(ws + 3538944);     // 768x768
  bf16*  fc1T = (bf16*)(ws + 4718592);      // 3072x768
  bf16*  fc2T = (bf16*)(ws + 9437184);      // 768x3072
  float* tA   = (float*)(ws + 14155776);    // 13504x768 f32
  float* tB   = (float*)(ws + 55640064);    // 13568x768 f32
  bf16*  hb   = (bf16*)(ws + 97320960);     // 13568x768 bf16
  bf16*  big  = (bf16*)(ws + 118161408);    // qkv / mlp-mid / im2col (79.5MB)
  bf16*  ao   = (bf16*)(ws + 201523200);    // 13568x768 bf16
  bf16*  vTb  = (bf16*)(ws + 222363648);    // V^T buffer (25.2MB)

  dim3 blk(256);

  auto apply_block = [&](float* xbuf, const BlkP& p, int nb, int ntok_) {
    const int M = nb * ntok_;
    const int gm = (M + 127) / 128;
    const int pad = (ntok_ == NTOK) ? 224 : 64;
    transpose4_k<<<dim3(6912), blk, 0, stream>>>(
        p.qkv_w, p.proj_w, p.fc1_w, p.fc2_w, qkvT, projT, fc1T, fc2T);
    ln_kernel<<<dim3((M + 3) / 4), blk, 0, stream>>>(xbuf, p.ln1_g, p.ln1_b, hb, M);
    gemm_db<false, false, bf16><<<dim3(gm * 18), blk, 0, stream>>>(
        hb, qkvT, p.qkv_b, nullptr, big, M, 2304, 768, 18);
    vtrans_kernel<<<dim3(nb, NHEAD), blk, 0, stream>>>(big, vTb, ntok_, pad);
    if (ntok_ == NTOK)
      attn_kernel<14><<<dim3(nb, NHEAD), blk, 0, stream>>>(big, vTb, ao, ntok_, pad);
    else
      attn_kernel<4><<<dim3(nb, NHEAD), blk, 0, stream>>>(big, vTb, ao, ntok_, pad);
    gemm_db<false, true, float><<<dim3(gm * 6), blk, 0, stream>>>(
        ao, projT, p.proj_b, xbuf, xbuf, M, 768, 768, 6);
    ln_kernel<<<dim3((M + 3) / 4), blk, 0, stream>>>(xbuf, p.ln2_g, p.ln2_b, hb, M);
    gemm_db<true, false, bf16><<<dim3(gm * 24), blk, 0, stream>>>(
        hb, fc1T, p.fc1_b, nullptr, big, M, 3072, 768, 24);
    gemm_db<false, true, float><<<dim3(gm * 6), blk, 0, stream>>>(
        big, fc2T, p.fc2_b, xbuf, xbuf, M, 768, 3072, 6);
  };

  // 1) patch embed: im2col -> GEMM(conv) -> assemble
  {
    int total = 13440 * 768;
    im2col_kernel<<<dim3((total + 255) / 256), blk, 0, stream>>>(xin, big);
    int nw = 768 * 768;
    cast_kernel<<<dim3((nw + 255) / 256), blk, 0, stream>>>(convw, qkvT, nw);
    gemm_db<false, false, bf16><<<dim3(105 * 6), blk, 0, stream>>>(
        big, qkvT, convb, nullptr, ao, 13440, 768, 768, 6);
    total = 13504 * 768;
    assemble_kernel<<<dim3((total + 255) / 256), blk, 0, stream>>>(ao, cls, pos, sie, cids, tA);
  }

  // 2) 11 stacked blocks (lead-dim DEPTH params)
  const float* bp[12];
  for (int i = 0; i < 12; ++i) bp[i] = (const float*)d_in[7 + i];
  for (int dd = 0; dd < DEPTH; ++dd) {
    BlkP p;
    p.ln1_g = bp[0] + dd * 768;                p.ln1_b = bp[1] + dd * 768;
    p.qkv_w = bp[2] + (size_t)dd * 768 * 2304; p.qkv_b = bp[3] + dd * 2304;
    p.proj_w = bp[4] + (size_t)dd * 768 * 768; p.proj_b = bp[5] + dd * 768;
    p.ln2_g = bp[6] + dd * 768;                p.ln2_b = bp[7] + dd * 768;
    p.fc1_w = bp[8] + (size_t)dd * 768 * 3072; p.fc1_b = bp[9] + dd * 3072;
    p.fc2_w = bp[10] + (size_t)dd * 3072 * 768; p.fc2_b = bp[11] + dd * 768;
    apply_block(tA, p, 64, NTOK);
  }

  // 3) b1 branch: f0 = LN(block(t))[:,0]
  (void)hipMemcpyAsync(tB, tA, (size_t)13504 * 768 * 4, hipMemcpyDeviceToDevice, stream);
  {
    BlkP p;
    p.ln1_g = (const float*)d_in[19]; p.ln1_b = (const float*)d_in[20];
    p.qkv_w = (const float*)d_in[21]; p.qkv_b = (const float*)d_in[22];
    p.proj_w = (const float*)d_in[23]; p.proj_b = (const float*)d_in[24];
    p.ln2_g = (const float*)d_in[25]; p.ln2_b = (const float*)d_in[26];
    p.fc1_w = (const float*)d_in[27]; p.fc1_b = (const float*)d_in[28];
    p.fc2_w = (const float*)d_in[29]; p.fc2_b = (const float*)d_in[30];
    apply_block(tB, p, 64, NTOK);
    ln_head_kernel<<<dim3(16), blk, 0, stream>>>(
        tB, NTOK, (const float*)d_in[31], (const float*)d_in[32], out, 64, 0);
  }

  // 4) b2 branch: 4 shuffled segments batched as 256 sequences of 53 tokens
  {
    int total = 256 * 53 * 768;
    gather_kernel<<<dim3((total + 255) / 256), blk, 0, stream>>>(tA, tB);
    BlkP p;
    p.ln1_g = (const float*)d_in[33]; p.ln1_b = (const float*)d_in[34];
    p.qkv_w = (const float*)d_in[35]; p.qkv_b = (const float*)d_in[36];
    p.proj_w = (const float*)d_in[37]; p.proj_b = (const float*)d_in[38];
    p.ln2_g = (const float*)d_in[39]; p.ln2_b = (const float*)d_in[40];
    p.fc1_w = (const float*)d_in[41]; p.fc1_b = (const float*)d_in[42];
    p.fc2_w = (const float*)d_in[43]; p.fc2_b = (const float*)d_in[44];
    apply_block(tB, p, 256, 53);
    ln_head_kernel<<<dim3(64), blk, 0, stream>>>(
        tB, 53, (const float*)d_in[45], (const float*)d_in[46], out, 256, 1);
  }
}